// Round 1
// baseline (1276.164 us; speedup 1.0000x reference)
//
#include <hip/hip_runtime.h>
#include <math.h>

// ---------- types ----------
typedef __attribute__((ext_vector_type(4))) float f32x4;
typedef __attribute__((ext_vector_type(4))) unsigned int u32x4;
typedef __attribute__((ext_vector_type(8))) unsigned short u16x8;
typedef __attribute__((ext_vector_type(4))) unsigned short u16x4;
typedef __attribute__((ext_vector_type(8))) __bf16 bf16x8;

union F8 { u32x4 u; u16x8 us; bf16x8 v; };

__device__ __forceinline__ unsigned short f2bf(float f) {
  unsigned int u = __float_as_uint(f);
  u += 0x7fffu + ((u >> 16) & 1u);
  return (unsigned short)(u >> 16);
}
__device__ __forceinline__ float bf2f(unsigned short s) {
  return __uint_as_float(((unsigned int)s) << 16);
}

// ---------- weight transpose+convert: in fp32 (K x N) -> out bf16 (N x K) ----------
__global__ __launch_bounds__(256) void wtrans(const float* __restrict__ in,
                                              unsigned short* __restrict__ out,
                                              int K, int N) {
  __shared__ float tile[32][33];
  int tx = threadIdx.x & 31, ty = threadIdx.x >> 5;
  int n0 = blockIdx.x * 32, k0 = blockIdx.y * 32;
#pragma unroll
  for (int i = 0; i < 32; i += 8)
    tile[ty + i][tx] = in[(size_t)(k0 + ty + i) * N + n0 + tx];
  __syncthreads();
#pragma unroll
  for (int i = 0; i < 32; i += 8)
    out[(size_t)(n0 + ty + i) * K + k0 + tx] = f2bf(tile[tx][ty + i]);
}

// ---------- flat fp32 -> bf16 ----------
__global__ __launch_bounds__(256) void f2bf_copy(const float* __restrict__ in,
                                                 unsigned short* __restrict__ out, int n) {
  int i = (blockIdx.x * 256 + threadIdx.x) * 4;
  if (i < n) {
    f32x4 v = *(const f32x4*)(in + i);
    u16x4 o;
#pragma unroll
    for (int j = 0; j < 4; j++) o[j] = f2bf(v[j]);
    *(u16x4*)(out + i) = o;
  }
}

// ---------- mods = silu(t_mod) @ adaLN_W + adaLN_b ; (B x 6144) fp32 ----------
__global__ __launch_bounds__(256) void mods_kernel(const float* __restrict__ t_mod,
                                                   const float* __restrict__ W,
                                                   const float* __restrict__ bias,
                                                   float* __restrict__ mods) {
  int b = blockIdx.y;
  int j = blockIdx.x * 256 + threadIdx.x;
  __shared__ float a_s[1024];
  for (int i = threadIdx.x; i < 1024; i += 256) {
    float tv = t_mod[b * 1024 + i];
    a_s[i] = tv / (1.0f + expf(-tv));
  }
  __syncthreads();
  float acc = bias[j];
  for (int k = 0; k < 1024; k++) acc = fmaf(a_s[k], W[(size_t)k * 6144 + j], acc);
  mods[b * 6144 + j] = acc;
}

// ---------- rmsnorm (+ optional adaLN modulation), fp32 in -> bf16 out ----------
__global__ __launch_bounds__(256) void rmsnorm_mod(const float* __restrict__ x,
                                                   const float* __restrict__ w,
                                                   const float* mods, int shift_off,
                                                   int scale_off,
                                                   unsigned short* __restrict__ out) {
  int row = blockIdx.x;
  int b = row >> 11;
  const float* xr = x + (size_t)row * 1024;
  int t = threadIdx.x;
  f32x4 xv = *(const f32x4*)(xr + t * 4);
  float ss = xv[0] * xv[0] + xv[1] * xv[1] + xv[2] * xv[2] + xv[3] * xv[3];
#pragma unroll
  for (int off = 32; off >= 1; off >>= 1) ss += __shfl_xor(ss, off, 64);
  __shared__ float red[4];
  if ((t & 63) == 0) red[t >> 6] = ss;
  __syncthreads();
  float tot = red[0] + red[1] + red[2] + red[3];
  float rr = rsqrtf(tot * (1.0f / 1024.0f) + 1e-6f);
  f32x4 wv = *(const f32x4*)(w + t * 4);
  f32x4 scv = (f32x4)(0.0f), shv = (f32x4)(0.0f);
  if (mods) {
    scv = *(const f32x4*)(mods + b * 6144 + scale_off + t * 4);
    shv = *(const f32x4*)(mods + b * 6144 + shift_off + t * 4);
  }
  u16x4 ov;
#pragma unroll
  for (int j = 0; j < 4; j++) {
    float n = xv[j] * rr * wv[j];
    ov[j] = f2bf(n * (1.0f + scv[j]) + shv[j]);
  }
  *(u16x4*)(out + (size_t)row * 1024 + t * 4) = ov;
}

// ---------- GEMM: C(MxN) = A(MxK,bf16) * Bt(NxK,bf16)^T ----------
// EPI 0: store bf16.  EPI 1: fp32 out = res + gate*acc (gate row = m>>11, stride 6144; null gate -> 1)
template <int EPI>
__global__ __launch_bounds__(256) void gemm_nt(const unsigned short* __restrict__ A,
                                               const unsigned short* __restrict__ Bt,
                                               void* Cout, const float* res,
                                               const float* gate, int M, int N, int K) {
  __shared__ unsigned short As[128][40];
  __shared__ unsigned short Bs[128][40];
  int tid = threadIdx.x;
  int row0 = blockIdx.x * 128, col0 = blockIdx.y * 128;
  int wave = tid >> 6, lane = tid & 63;
  int wm = (wave & 1) * 64, wn = (wave >> 1) * 64;
  int mrow = lane & 15, grp = lane >> 4;
  f32x4 acc[4][4];
#pragma unroll
  for (int i = 0; i < 4; i++)
#pragma unroll
    for (int j = 0; j < 4; j++) acc[i][j] = (f32x4)(0.0f);

  int sr = tid >> 1, sk = (tid & 1) * 16;
  const unsigned short* pa = A + (size_t)(row0 + sr) * K + sk;
  const unsigned short* pb = Bt + (size_t)(col0 + sr) * K + sk;

  for (int k0 = 0; k0 < K; k0 += 32) {
    __syncthreads();
    u32x4 a0 = *(const u32x4*)(pa + k0);
    u32x4 a1 = *(const u32x4*)(pa + k0 + 8);
    u32x4 b0 = *(const u32x4*)(pb + k0);
    u32x4 b1 = *(const u32x4*)(pb + k0 + 8);
    *(u32x4*)&As[sr][sk] = a0;
    *(u32x4*)&As[sr][sk + 8] = a1;
    *(u32x4*)&Bs[sr][sk] = b0;
    *(u32x4*)&Bs[sr][sk + 8] = b1;
    __syncthreads();
    bf16x8 af[4], bfr[4];
#pragma unroll
    for (int i = 0; i < 4; i++) {
      af[i] = *(const bf16x8*)&As[wm + i * 16 + mrow][grp * 8];
      bfr[i] = *(const bf16x8*)&Bs[wn + i * 16 + mrow][grp * 8];
    }
#pragma unroll
    for (int i = 0; i < 4; i++)
#pragma unroll
      for (int j = 0; j < 4; j++)
        acc[i][j] = __builtin_amdgcn_mfma_f32_16x16x32_bf16(af[i], bfr[j], acc[i][j], 0, 0, 0);
  }
#pragma unroll
  for (int i = 0; i < 4; i++) {
    int rbase = row0 + wm + i * 16 + grp * 4;
#pragma unroll
    for (int j = 0; j < 4; j++) {
      int col = col0 + wn + j * 16 + mrow;
      f32x4 a = acc[i][j];
#pragma unroll
      for (int r = 0; r < 4; r++) {
        size_t idx = (size_t)(rbase + r) * N + col;
        if (EPI == 0) {
          ((unsigned short*)Cout)[idx] = f2bf(a[r]);
        } else {
          float g = gate ? gate[((rbase + r) >> 11) * 6144 + col] : 1.0f;
          ((float*)Cout)[idx] = res[idx] + g * a[r];
        }
      }
    }
  }
}

// ---------- V transpose: in bf16 [b][l][..h..][d] -> out bf16 [b*H+h][d][l] ----------
__global__ __launch_bounds__(256) void vtrans(const unsigned short* __restrict__ in,
                                              unsigned short* __restrict__ out,
                                              int lstride, size_t bstride, int Lk) {
  int lt = blockIdx.x, h = blockIdx.y, b = blockIdx.z;
  __shared__ unsigned short tile[64][72];
  int t = threadIdx.x;
  int lrow = t >> 2, dp = (t & 3) * 16;
  const unsigned short* src =
      in + (size_t)b * bstride + (size_t)(lt * 64 + lrow) * lstride + h * 64 + dp;
  u32x4 v0 = *(const u32x4*)src;
  u32x4 v1 = *(const u32x4*)(src + 8);
  *(u32x4*)&tile[lrow][dp] = v0;
  *(u32x4*)&tile[lrow][dp + 8] = v1;
  __syncthreads();
  int d = t >> 2, lp = (t & 3) * 16;
  u16x8 t0, t1;
#pragma unroll
  for (int i = 0; i < 8; i++) {
    t0[i] = tile[lp + i][d];
    t1[i] = tile[lp + 8 + i][d];
  }
  unsigned short* dst = out + ((size_t)(b * 16 + h) * 64 + d) * Lk + lt * 64 + lp;
  *(u16x8*)dst = t0;
  *(u16x8*)(dst + 8) = t1;
}

// ---------- fused flash attention, 1 wave per (b,h,16-query tile) ----------
__device__ __forceinline__ void rope_frag(F8& f, const float* cosp, const float* sinp) {
  f32x4 c = *(const f32x4*)cosp;
  f32x4 s = *(const f32x4*)sinp;
#pragma unroll
  for (int j = 0; j < 4; j++) {
    float xr = bf2f(f.us[2 * j]), xi = bf2f(f.us[2 * j + 1]);
    f.us[2 * j] = f2bf(xr * c[j] - xi * s[j]);
    f.us[2 * j + 1] = f2bf(xr * s[j] + xi * c[j]);
  }
}

template <bool ROPE>
__global__ __launch_bounds__(64) void attn(const unsigned short* __restrict__ qb, int q_ls,
                                           size_t q_bs, const unsigned short* __restrict__ kb,
                                           int k_ls, size_t k_bs,
                                           const unsigned short* __restrict__ vt,
                                           unsigned short* __restrict__ ob, int o_ls,
                                           size_t o_bs, const float* fcos, const float* fsin,
                                           int Lk) {
  int qt = blockIdx.x, h = blockIdx.y, b = blockIdx.z;
  int lane = threadIdx.x;
  int mrow = lane & 15, grp = lane >> 4;
  int q0 = qt * 16;
  __shared__ unsigned short plds[16 * 32];

  const unsigned short* qp =
      qb + (size_t)b * q_bs + (size_t)(q0 + mrow) * q_ls + h * 64 + grp * 8;
  bf16x8 qf[2];
#pragma unroll
  for (int c = 0; c < 2; c++) {
    F8 f;
    f.u = *(const u32x4*)(qp + c * 32);
    if (ROPE)
      rope_frag(f, fcos + (q0 + mrow) * 32 + c * 16 + grp * 4,
                fsin + (q0 + mrow) * 32 + c * 16 + grp * 4);
    qf[c] = f.v;
  }
  const unsigned short* vtb = vt + (size_t)(b * 16 + h) * 64 * Lk;
  const float K2 = 0.125f * 1.4426950408889634f;  // scale * log2(e)
  float m_run[4], l_run[4];
  f32x4 o[4];
#pragma unroll
  for (int r = 0; r < 4; r++) { m_run[r] = -INFINITY; l_run[r] = 0.f; }
#pragma unroll
  for (int nt = 0; nt < 4; nt++) o[nt] = (f32x4)(0.0f);

  for (int k0 = 0; k0 < Lk; k0 += 32) {
    f32x4 sc[2];
#pragma unroll
    for (int si = 0; si < 2; si++) {
      int krow = k0 + si * 16 + mrow;
      const unsigned short* kp =
          kb + (size_t)b * k_bs + (size_t)krow * k_ls + h * 64 + grp * 8;
      F8 f0, f1;
      f0.u = *(const u32x4*)kp;
      f1.u = *(const u32x4*)(kp + 32);
      if (ROPE) {
        rope_frag(f0, fcos + krow * 32 + grp * 4, fsin + krow * 32 + grp * 4);
        rope_frag(f1, fcos + krow * 32 + 16 + grp * 4, fsin + krow * 32 + 16 + grp * 4);
      }
      f32x4 s = (f32x4)(0.0f);
      s = __builtin_amdgcn_mfma_f32_16x16x32_bf16(qf[0], f0.v, s, 0, 0, 0);
      s = __builtin_amdgcn_mfma_f32_16x16x32_bf16(qf[1], f1.v, s, 0, 0, 0);
      sc[si] = s;
    }
    float alpha[4], pa[4], pb_[4];
#pragma unroll
    for (int r = 0; r < 4; r++) {
      float sa_ = sc[0][r] * K2, sb_ = sc[1][r] * K2;
      float v = fmaxf(sa_, sb_);
#pragma unroll
      for (int off = 8; off >= 1; off >>= 1) v = fmaxf(v, __shfl_xor(v, off, 64));
      float mnew = fmaxf(m_run[r], v);
      alpha[r] = exp2f(m_run[r] - mnew);
      m_run[r] = mnew;
      pa[r] = exp2f(sa_ - mnew);
      pb_[r] = exp2f(sb_ - mnew);
      float rs = pa[r] + pb_[r];
#pragma unroll
      for (int off = 8; off >= 1; off >>= 1) rs += __shfl_xor(rs, off, 64);
      l_run[r] = l_run[r] * alpha[r] + rs;
    }
    __syncthreads();
#pragma unroll
    for (int r = 0; r < 4; r++) {
      plds[(grp * 4 + r) * 32 + mrow] = f2bf(pa[r]);
      plds[(grp * 4 + r) * 32 + 16 + mrow] = f2bf(pb_[r]);
    }
    __syncthreads();
    bf16x8 pf = *(const bf16x8*)&plds[mrow * 32 + grp * 8];
#pragma unroll
    for (int nt = 0; nt < 4; nt++) {
#pragma unroll
      for (int r = 0; r < 4; r++) o[nt][r] *= alpha[r];
      F8 vf;
      vf.u = *(const u32x4*)(vtb + (size_t)(nt * 16 + mrow) * Lk + k0 + grp * 8);
      o[nt] = __builtin_amdgcn_mfma_f32_16x16x32_bf16(pf, vf.v, o[nt], 0, 0, 0);
    }
  }
  unsigned short* op = ob + (size_t)b * o_bs + h * 64;
#pragma unroll
  for (int nt = 0; nt < 4; nt++) {
#pragma unroll
    for (int r = 0; r < 4; r++) {
      int row = q0 + grp * 4 + r;
      op[(size_t)row * o_ls + nt * 16 + mrow] = f2bf(o[nt][r] / l_run[r]);
    }
  }
}

// ---------- swiglu: g = silu(g) * u (bf16, in-place on g) ----------
__global__ __launch_bounds__(256) void swiglu(unsigned short* __restrict__ g,
                                              const unsigned short* __restrict__ u, int n) {
  int i = (blockIdx.x * 256 + threadIdx.x) * 8;
  if (i >= n) return;
  F8 gv, uv;
  gv.u = *(const u32x4*)(g + i);
  uv.u = *(const u32x4*)(u + i);
  u16x8 h;
#pragma unroll
  for (int j = 0; j < 8; j++) {
    float gf = bf2f(gv.us[j]), uf = bf2f(uv.us[j]);
    h[j] = f2bf(gf / (1.0f + expf(-gf)) * uf);
  }
  *(u16x8*)(g + i) = h;
}

// ---------- launcher ----------
extern "C" void kernel_launch(void* const* d_in, const int* in_sizes, int n_in, void* d_out,
                              int out_size, void* d_ws, size_t ws_size, hipStream_t stream) {
  const float* x = (const float*)d_in[0];
  const float* t_mod = (const float*)d_in[1];
  const float* audio = (const float*)d_in[2];
  const float* fcos = (const float*)d_in[3];
  const float* fsin = (const float*)d_in[4];
  const float* norm1_w = (const float*)d_in[5];
  const float* norm2_w = (const float*)d_in[6];
  const float* norm3_w = (const float*)d_in[7];
  const float* W_qkv = (const float*)d_in[8];
  const float* W_sa = (const float*)d_in[9];
  const float* W_q = (const float*)d_in[10];
  const float* W_kv = (const float*)d_in[11];
  const float* W_ca = (const float*)d_in[12];
  const float* W_gate = (const float*)d_in[13];
  const float* W_up = (const float*)d_in[14];
  const float* W_down = (const float*)d_in[15];
  const float* adaW = (const float*)d_in[16];
  const float* adaB = (const float*)d_in[17];

  char* ws = (char*)d_ws;
  float* x_res = (float*)d_out;  // residual stream lives in d_out (fp32)

  // workspace layout (bytes)
  unsigned short* wt_qkv = (unsigned short*)(ws + 0);           // 3072x1024
  unsigned short* wt_sa = (unsigned short*)(ws + 6291456);      // 1024x1024
  unsigned short* wt_q = (unsigned short*)(ws + 8388608);       // 1024x1024
  unsigned short* wt_kv = (unsigned short*)(ws + 10485760);     // 2048x768
  unsigned short* wt_ca = (unsigned short*)(ws + 13631488);     // 1024x1024
  unsigned short* wt_gate = (unsigned short*)(ws + 15728640);   // 4096x1024
  unsigned short* wt_up = (unsigned short*)(ws + 24117248);     // 4096x1024
  unsigned short* wt_down = (unsigned short*)(ws + 32505856);   // 1024x4096
  unsigned short* audio_bf = (unsigned short*)(ws + 40894464);  // 1024x768
  float* mods = (float*)(ws + 42467328);                        // 2x6144 fp32
  // phase 1
  unsigned short* x_sa = (unsigned short*)(ws + 42516480);  // 4096x1024
  unsigned short* qkv = (unsigned short*)(ws + 50905088);   // 4096x3072
  unsigned short* vt_s = (unsigned short*)(ws + 76070912);  // 32x64x2048
  unsigned short* sa = (unsigned short*)(ws + 84459520);    // 4096x1024
  // phase 2 (aliases phase-1 dead buffers)
  unsigned short* xn = (unsigned short*)(ws + 42516480);
  unsigned short* qc = (unsigned short*)(ws + 50905088);
  unsigned short* kvc = (unsigned short*)(ws + 59293696);  // 1024x2048
  unsigned short* vt_c = (unsigned short*)(ws + 63488000);  // 32x64x512
  unsigned short* ca = (unsigned short*)(ws + 65585152);    // 4096x1024
  // phase 3
  unsigned short* x_mlp = (unsigned short*)(ws + 42516480);
  unsigned short* gbuf = (unsigned short*)(ws + 50905088);  // 4096x4096
  unsigned short* ubuf = (unsigned short*)(ws + 84459520);  // 4096x4096  (peak 118 MB)

  // weight prep
  wtrans<<<dim3(96, 32), 256, 0, stream>>>(W_qkv, wt_qkv, 1024, 3072);
  wtrans<<<dim3(32, 32), 256, 0, stream>>>(W_sa, wt_sa, 1024, 1024);
  wtrans<<<dim3(32, 32), 256, 0, stream>>>(W_q, wt_q, 1024, 1024);
  wtrans<<<dim3(64, 24), 256, 0, stream>>>(W_kv, wt_kv, 768, 2048);
  wtrans<<<dim3(32, 32), 256, 0, stream>>>(W_ca, wt_ca, 1024, 1024);
  wtrans<<<dim3(128, 32), 256, 0, stream>>>(W_gate, wt_gate, 1024, 4096);
  wtrans<<<dim3(128, 32), 256, 0, stream>>>(W_up, wt_up, 1024, 4096);
  wtrans<<<dim3(32, 128), 256, 0, stream>>>(W_down, wt_down, 4096, 1024);
  f2bf_copy<<<768, 256, 0, stream>>>(audio, audio_bf, 786432);
  mods_kernel<<<dim3(24, 2), 256, 0, stream>>>(t_mod, adaW, adaB, mods);

  // self-attention block
  rmsnorm_mod<<<4096, 256, 0, stream>>>(x, norm1_w, mods, 0, 1024, x_sa);
  gemm_nt<0><<<dim3(32, 24), 256, 0, stream>>>(x_sa, wt_qkv, qkv, nullptr, nullptr, 4096, 3072, 1024);
  vtrans<<<dim3(32, 16, 2), 256, 0, stream>>>(qkv + 2048, vt_s, 3072, 6291456, 2048);
  attn<true><<<dim3(128, 16, 2), 64, 0, stream>>>(qkv, 3072, 6291456, qkv + 1024, 3072,
                                                  6291456, vt_s, sa, 1024, 2097152, fcos, fsin, 2048);
  gemm_nt<1><<<dim3(32, 8), 256, 0, stream>>>(sa, wt_sa, x_res, x, mods + 2048, 4096, 1024, 1024);

  // cross-attention block
  rmsnorm_mod<<<4096, 256, 0, stream>>>(x_res, norm2_w, nullptr, 0, 0, xn);
  gemm_nt<0><<<dim3(32, 8), 256, 0, stream>>>(xn, wt_q, qc, nullptr, nullptr, 4096, 1024, 1024);
  gemm_nt<0><<<dim3(8, 16), 256, 0, stream>>>(audio_bf, wt_kv, kvc, nullptr, nullptr, 1024, 2048, 768);
  vtrans<<<dim3(8, 16, 2), 256, 0, stream>>>(kvc + 1024, vt_c, 2048, 1048576, 512);
  attn<false><<<dim3(128, 16, 2), 64, 0, stream>>>(qc, 1024, 2097152, kvc, 2048, 1048576,
                                                   vt_c, ca, 1024, 2097152, nullptr, nullptr, 512);
  gemm_nt<1><<<dim3(32, 8), 256, 0, stream>>>(ca, wt_ca, x_res, x_res, nullptr, 4096, 1024, 1024);

  // MLP block
  rmsnorm_mod<<<4096, 256, 0, stream>>>(x_res, norm3_w, mods, 3072, 4096, x_mlp);
  gemm_nt<0><<<dim3(32, 32), 256, 0, stream>>>(x_mlp, wt_gate, gbuf, nullptr, nullptr, 4096, 4096, 1024);
  gemm_nt<0><<<dim3(32, 32), 256, 0, stream>>>(x_mlp, wt_up, ubuf, nullptr, nullptr, 4096, 4096, 1024);
  swiglu<<<8192, 256, 0, stream>>>(gbuf, ubuf, 16777216);
  gemm_nt<1><<<dim3(32, 8), 256, 0, stream>>>(gbuf, wt_down, x_res, x_res, mods + 5120, 4096, 1024, 4096);
}

// Round 2
// 880.406 us; speedup vs baseline: 1.4495x; 1.4495x over previous
//
#include <hip/hip_runtime.h>
#include <math.h>

// ---------- types ----------
typedef __attribute__((ext_vector_type(4))) float f32x4;
typedef __attribute__((ext_vector_type(4))) unsigned int u32x4;
typedef __attribute__((ext_vector_type(8))) unsigned short u16x8;
typedef __attribute__((ext_vector_type(4))) unsigned short u16x4;
typedef __attribute__((ext_vector_type(8))) __bf16 bf16x8;

union F8 { u32x4 u; u16x8 us; bf16x8 v; };

__device__ __forceinline__ unsigned short f2bf(float f) {
  unsigned int u = __float_as_uint(f);
  u += 0x7fffu + ((u >> 16) & 1u);
  return (unsigned short)(u >> 16);
}
__device__ __forceinline__ float bf2f(unsigned short s) {
  return __uint_as_float(((unsigned int)s) << 16);
}

// ---------- weight transpose+convert: in fp32 (K x N) -> out bf16 (N x K) ----------
__global__ __launch_bounds__(256) void wtrans(const float* __restrict__ in,
                                              unsigned short* __restrict__ out,
                                              int K, int N) {
  __shared__ float tile[32][33];
  int tx = threadIdx.x & 31, ty = threadIdx.x >> 5;
  int n0 = blockIdx.x * 32, k0 = blockIdx.y * 32;
#pragma unroll
  for (int i = 0; i < 32; i += 8)
    tile[ty + i][tx] = in[(size_t)(k0 + ty + i) * N + n0 + tx];
  __syncthreads();
#pragma unroll
  for (int i = 0; i < 32; i += 8)
    out[(size_t)(n0 + ty + i) * K + k0 + tx] = f2bf(tile[tx][ty + i]);
}

// ---------- flat fp32 -> bf16 ----------
__global__ __launch_bounds__(256) void f2bf_copy(const float* __restrict__ in,
                                                 unsigned short* __restrict__ out, int n) {
  int i = (blockIdx.x * 256 + threadIdx.x) * 4;
  if (i < n) {
    f32x4 v = *(const f32x4*)(in + i);
    u16x4 o;
#pragma unroll
    for (int j = 0; j < 4; j++) o[j] = f2bf(v[j]);
    *(u16x4*)(out + i) = o;
  }
}

// ---------- mods = silu(t_mod) @ adaLN_W + adaLN_b ; (B x 6144) fp32 ----------
__global__ __launch_bounds__(256) void mods_kernel(const float* __restrict__ t_mod,
                                                   const float* __restrict__ W,
                                                   const float* __restrict__ bias,
                                                   float* __restrict__ mods) {
  int b = blockIdx.y;
  int j = blockIdx.x * 256 + threadIdx.x;
  __shared__ float a_s[1024];
  for (int i = threadIdx.x; i < 1024; i += 256) {
    float tv = t_mod[b * 1024 + i];
    a_s[i] = tv / (1.0f + expf(-tv));
  }
  __syncthreads();
  float acc = bias[j];
  for (int k = 0; k < 1024; k++) acc = fmaf(a_s[k], W[(size_t)k * 6144 + j], acc);
  mods[b * 6144 + j] = acc;
}

// ---------- rmsnorm (+ optional adaLN modulation), fp32 in -> bf16 out ----------
__global__ __launch_bounds__(256) void rmsnorm_mod(const float* __restrict__ x,
                                                   const float* __restrict__ w,
                                                   const float* mods, int shift_off,
                                                   int scale_off,
                                                   unsigned short* __restrict__ out) {
  int row = blockIdx.x;
  int b = row >> 11;
  const float* xr = x + (size_t)row * 1024;
  int t = threadIdx.x;
  f32x4 xv = *(const f32x4*)(xr + t * 4);
  float ss = xv[0] * xv[0] + xv[1] * xv[1] + xv[2] * xv[2] + xv[3] * xv[3];
#pragma unroll
  for (int off = 32; off >= 1; off >>= 1) ss += __shfl_xor(ss, off, 64);
  __shared__ float red[4];
  if ((t & 63) == 0) red[t >> 6] = ss;
  __syncthreads();
  float tot = red[0] + red[1] + red[2] + red[3];
  float rr = rsqrtf(tot * (1.0f / 1024.0f) + 1e-6f);
  f32x4 wv = *(const f32x4*)(w + t * 4);
  f32x4 scv = (f32x4)(0.0f), shv = (f32x4)(0.0f);
  if (mods) {
    scv = *(const f32x4*)(mods + b * 6144 + scale_off + t * 4);
    shv = *(const f32x4*)(mods + b * 6144 + shift_off + t * 4);
  }
  u16x4 ov;
#pragma unroll
  for (int j = 0; j < 4; j++) {
    float n = xv[j] * rr * wv[j];
    ov[j] = f2bf(n * (1.0f + scv[j]) + shv[j]);
  }
  *(u16x4*)(out + (size_t)row * 1024 + t * 4) = ov;
}

// ---------- GEMM: C(MxN) = A(MxK,bf16) * Bt(NxK,bf16)^T ----------
template <int EPI>
__global__ __launch_bounds__(256) void gemm_nt(const unsigned short* __restrict__ A,
                                               const unsigned short* __restrict__ Bt,
                                               void* Cout, const float* res,
                                               const float* gate, int M, int N, int K) {
  __shared__ unsigned short As[128][40];
  __shared__ unsigned short Bs[128][40];
  int tid = threadIdx.x;
  int row0 = blockIdx.x * 128, col0 = blockIdx.y * 128;
  int wave = tid >> 6, lane = tid & 63;
  int wm = (wave & 1) * 64, wn = (wave >> 1) * 64;
  int mrow = lane & 15, grp = lane >> 4;
  f32x4 acc[4][4];
#pragma unroll
  for (int i = 0; i < 4; i++)
#pragma unroll
    for (int j = 0; j < 4; j++) acc[i][j] = (f32x4)(0.0f);

  int sr = tid >> 1, sk = (tid & 1) * 16;
  const unsigned short* pa = A + (size_t)(row0 + sr) * K + sk;
  const unsigned short* pb = Bt + (size_t)(col0 + sr) * K + sk;

  for (int k0 = 0; k0 < K; k0 += 32) {
    __syncthreads();
    u32x4 a0 = *(const u32x4*)(pa + k0);
    u32x4 a1 = *(const u32x4*)(pa + k0 + 8);
    u32x4 b0 = *(const u32x4*)(pb + k0);
    u32x4 b1 = *(const u32x4*)(pb + k0 + 8);
    *(u32x4*)&As[sr][sk] = a0;
    *(u32x4*)&As[sr][sk + 8] = a1;
    *(u32x4*)&Bs[sr][sk] = b0;
    *(u32x4*)&Bs[sr][sk + 8] = b1;
    __syncthreads();
    bf16x8 af[4], bfr[4];
#pragma unroll
    for (int i = 0; i < 4; i++) {
      af[i] = *(const bf16x8*)&As[wm + i * 16 + mrow][grp * 8];
      bfr[i] = *(const bf16x8*)&Bs[wn + i * 16 + mrow][grp * 8];
    }
#pragma unroll
    for (int i = 0; i < 4; i++)
#pragma unroll
      for (int j = 0; j < 4; j++)
        acc[i][j] = __builtin_amdgcn_mfma_f32_16x16x32_bf16(af[i], bfr[j], acc[i][j], 0, 0, 0);
  }
#pragma unroll
  for (int i = 0; i < 4; i++) {
    int rbase = row0 + wm + i * 16 + grp * 4;
#pragma unroll
    for (int j = 0; j < 4; j++) {
      int col = col0 + wn + j * 16 + mrow;
      f32x4 a = acc[i][j];
#pragma unroll
      for (int r = 0; r < 4; r++) {
        size_t idx = (size_t)(rbase + r) * N + col;
        if (EPI == 0) {
          ((unsigned short*)Cout)[idx] = f2bf(a[r]);
        } else {
          float g = gate ? gate[((rbase + r) >> 11) * 6144 + col] : 1.0f;
          ((float*)Cout)[idx] = res[idx] + g * a[r];
        }
      }
    }
  }
}

// ---------- V transpose: in bf16 [b][l][..h..][d] -> out bf16 [b*H+h][d][l] ----------
__global__ __launch_bounds__(256) void vtrans(const unsigned short* __restrict__ in,
                                              unsigned short* __restrict__ out,
                                              int lstride, size_t bstride, int Lk) {
  int lt = blockIdx.x, h = blockIdx.y, b = blockIdx.z;
  __shared__ unsigned short tile[64][72];
  int t = threadIdx.x;
  int lrow = t >> 2, dp = (t & 3) * 16;
  const unsigned short* src =
      in + (size_t)b * bstride + (size_t)(lt * 64 + lrow) * lstride + h * 64 + dp;
  u32x4 v0 = *(const u32x4*)src;
  u32x4 v1 = *(const u32x4*)(src + 8);
  *(u32x4*)&tile[lrow][dp] = v0;
  *(u32x4*)&tile[lrow][dp + 8] = v1;
  __syncthreads();
  int d = t >> 2, lp = (t & 3) * 16;
  u16x8 t0, t1;
#pragma unroll
  for (int i = 0; i < 8; i++) {
    t0[i] = tile[lp + i][d];
    t1[i] = tile[lp + 8 + i][d];
  }
  unsigned short* dst = out + ((size_t)(b * 16 + h) * 64 + d) * Lk + lt * 64 + lp;
  *(u16x8*)dst = t0;
  *(u16x8*)(dst + 8) = t1;
}

// ---------- RoPE applied in-place to q,k planes of qkv [b][l][3][16][64] ----------
__global__ __launch_bounds__(256) void rope_qk(unsigned short* __restrict__ qkv,
                                               const float* __restrict__ fcos,
                                               const float* __restrict__ fsin) {
  int l = blockIdx.x, b = blockIdx.y;
  int t = threadIdx.x;
  int plane = t >> 7, rem = t & 127;
  int hh = rem >> 3, off = (rem & 7) * 8;
  unsigned short* p = qkv + (((size_t)(b * 2048 + l) * 3 + plane) * 16 + hh) * 64 + off;
  F8 f;
  f.u = *(const u32x4*)p;
  f32x4 c = *(const f32x4*)(fcos + l * 32 + off / 2);
  f32x4 s = *(const f32x4*)(fsin + l * 32 + off / 2);
  u16x8 o;
#pragma unroll
  for (int j = 0; j < 4; j++) {
    float xr = bf2f(f.us[2 * j]), xi = bf2f(f.us[2 * j + 1]);
    o[2 * j] = f2bf(xr * c[j] - xi * s[j]);
    o[2 * j + 1] = f2bf(xr * s[j] + xi * c[j]);
  }
  *(u16x8*)p = o;
}

// ---------- flash attention: 256 thr (4 waves), 64 queries/block, 64-key LDS tiles ----------
__global__ __launch_bounds__(256) void attn2(const unsigned short* __restrict__ qb, int q_ls,
                                             size_t q_bs, const unsigned short* __restrict__ kb,
                                             int k_ls, size_t k_bs,
                                             const unsigned short* __restrict__ vt,
                                             unsigned short* __restrict__ ob, int o_ls,
                                             size_t o_bs, int Lk) {
  int qt = blockIdx.x, h = blockIdx.y, b = blockIdx.z;
  int tid = threadIdx.x;
  int w = tid >> 6, lane = tid & 63;
  int mrow = lane & 15, grp = lane >> 4;
  int q0 = qt * 64 + w * 16;
  __shared__ unsigned short Ks[64][72];
  __shared__ unsigned short Vs[64][72];
  __shared__ unsigned short Ps[4][16][72];

  const unsigned short* qp =
      qb + (size_t)b * q_bs + (size_t)(q0 + mrow) * q_ls + h * 64 + grp * 8;
  bf16x8 qf0, qf1;
  {
    F8 f;
    f.u = *(const u32x4*)qp;
    qf0 = f.v;
    f.u = *(const u32x4*)(qp + 32);
    qf1 = f.v;
  }
  const unsigned short* kbb = kb + (size_t)b * k_bs + h * 64;
  const unsigned short* vtb = vt + (size_t)(b * 16 + h) * 64 * Lk;

  const float K2 = 0.125f * 1.4426950408889634f;  // scale * log2(e)
  float m_run[4], l_run[4];
  f32x4 o[4];
#pragma unroll
  for (int r = 0; r < 4; r++) { m_run[r] = -INFINITY; l_run[r] = 0.f; }
#pragma unroll
  for (int nt = 0; nt < 4; nt++) o[nt] = (f32x4)(0.0f);

  int r1 = tid >> 3, o1 = (tid & 7) * 8;
  for (int k0 = 0; k0 < Lk; k0 += 64) {
    __syncthreads();
    {
      u32x4 kv1 = *(const u32x4*)(kbb + (size_t)(k0 + r1) * k_ls + o1);
      u32x4 kv2 = *(const u32x4*)(kbb + (size_t)(k0 + r1 + 32) * k_ls + o1);
      u32x4 vv1 = *(const u32x4*)(vtb + (size_t)r1 * Lk + k0 + o1);
      u32x4 vv2 = *(const u32x4*)(vtb + (size_t)(r1 + 32) * Lk + k0 + o1);
      *(u32x4*)&Ks[r1][o1] = kv1;
      *(u32x4*)&Ks[r1 + 32][o1] = kv2;
      *(u32x4*)&Vs[r1][o1] = vv1;
      *(u32x4*)&Vs[r1 + 32][o1] = vv2;
    }
    __syncthreads();
    // scores: 16 q x 64 k
    f32x4 sc[4];
#pragma unroll
    for (int si = 0; si < 4; si++) {
      F8 kf0, kf1;
      kf0.u = *(const u32x4*)&Ks[si * 16 + mrow][grp * 8];
      kf1.u = *(const u32x4*)&Ks[si * 16 + mrow][32 + grp * 8];
      f32x4 s = (f32x4)(0.0f);
      s = __builtin_amdgcn_mfma_f32_16x16x32_bf16(qf0, kf0.v, s, 0, 0, 0);
      s = __builtin_amdgcn_mfma_f32_16x16x32_bf16(qf1, kf1.v, s, 0, 0, 0);
      sc[si] = s;
    }
    float alpha[4], p[4][4];
#pragma unroll
    for (int r = 0; r < 4; r++) {
      float v = fmaxf(fmaxf(sc[0][r], sc[1][r]), fmaxf(sc[2][r], sc[3][r])) * K2;
#pragma unroll
      for (int off = 8; off >= 1; off >>= 1) v = fmaxf(v, __shfl_xor(v, off, 64));
      float mnew = fmaxf(m_run[r], v);
      alpha[r] = exp2f(m_run[r] - mnew);
      m_run[r] = mnew;
      float rs = 0.f;
#pragma unroll
      for (int si = 0; si < 4; si++) {
        p[si][r] = exp2f(sc[si][r] * K2 - mnew);
        rs += p[si][r];
      }
#pragma unroll
      for (int off = 8; off >= 1; off >>= 1) rs += __shfl_xor(rs, off, 64);
      l_run[r] = l_run[r] * alpha[r] + rs;
    }
#pragma unroll
    for (int si = 0; si < 4; si++)
#pragma unroll
      for (int r = 0; r < 4; r++)
        Ps[w][grp * 4 + r][si * 16 + mrow] = f2bf(p[si][r]);
    __syncthreads();
    bf16x8 pf0 = *(const bf16x8*)&Ps[w][mrow][grp * 8];
    bf16x8 pf1 = *(const bf16x8*)&Ps[w][mrow][32 + grp * 8];
#pragma unroll
    for (int nt = 0; nt < 4; nt++) {
#pragma unroll
      for (int r = 0; r < 4; r++) o[nt][r] *= alpha[r];
      F8 vf0, vf1;
      vf0.u = *(const u32x4*)&Vs[nt * 16 + mrow][grp * 8];
      vf1.u = *(const u32x4*)&Vs[nt * 16 + mrow][32 + grp * 8];
      o[nt] = __builtin_amdgcn_mfma_f32_16x16x32_bf16(pf0, vf0.v, o[nt], 0, 0, 0);
      o[nt] = __builtin_amdgcn_mfma_f32_16x16x32_bf16(pf1, vf1.v, o[nt], 0, 0, 0);
    }
  }
  unsigned short* op = ob + (size_t)b * o_bs + h * 64;
#pragma unroll
  for (int nt = 0; nt < 4; nt++)
#pragma unroll
    for (int r = 0; r < 4; r++) {
      int row = q0 + grp * 4 + r;
      op[(size_t)row * o_ls + nt * 16 + mrow] = f2bf(o[nt][r] / l_run[r]);
    }
}

// ---------- swiglu: g = silu(g) * u (bf16, in-place on g) ----------
__global__ __launch_bounds__(256) void swiglu(unsigned short* __restrict__ g,
                                              const unsigned short* __restrict__ u, int n) {
  int i = (blockIdx.x * 256 + threadIdx.x) * 8;
  if (i >= n) return;
  F8 gv, uv;
  gv.u = *(const u32x4*)(g + i);
  uv.u = *(const u32x4*)(u + i);
  u16x8 h;
#pragma unroll
  for (int j = 0; j < 8; j++) {
    float gf = bf2f(gv.us[j]), uf = bf2f(uv.us[j]);
    h[j] = f2bf(gf / (1.0f + expf(-gf)) * uf);
  }
  *(u16x8*)(g + i) = h;
}

// ---------- launcher ----------
extern "C" void kernel_launch(void* const* d_in, const int* in_sizes, int n_in, void* d_out,
                              int out_size, void* d_ws, size_t ws_size, hipStream_t stream) {
  const float* x = (const float*)d_in[0];
  const float* t_mod = (const float*)d_in[1];
  const float* audio = (const float*)d_in[2];
  const float* fcos = (const float*)d_in[3];
  const float* fsin = (const float*)d_in[4];
  const float* norm1_w = (const float*)d_in[5];
  const float* norm2_w = (const float*)d_in[6];
  const float* norm3_w = (const float*)d_in[7];
  const float* W_qkv = (const float*)d_in[8];
  const float* W_sa = (const float*)d_in[9];
  const float* W_q = (const float*)d_in[10];
  const float* W_kv = (const float*)d_in[11];
  const float* W_ca = (const float*)d_in[12];
  const float* W_gate = (const float*)d_in[13];
  const float* W_up = (const float*)d_in[14];
  const float* W_down = (const float*)d_in[15];
  const float* adaW = (const float*)d_in[16];
  const float* adaB = (const float*)d_in[17];

  char* ws = (char*)d_ws;
  float* x_res = (float*)d_out;  // residual stream lives in d_out (fp32)

  unsigned short* wt_qkv = (unsigned short*)(ws + 0);
  unsigned short* wt_sa = (unsigned short*)(ws + 6291456);
  unsigned short* wt_q = (unsigned short*)(ws + 8388608);
  unsigned short* wt_kv = (unsigned short*)(ws + 10485760);
  unsigned short* wt_ca = (unsigned short*)(ws + 13631488);
  unsigned short* wt_gate = (unsigned short*)(ws + 15728640);
  unsigned short* wt_up = (unsigned short*)(ws + 24117248);
  unsigned short* wt_down = (unsigned short*)(ws + 32505856);
  unsigned short* audio_bf = (unsigned short*)(ws + 40894464);
  float* mods = (float*)(ws + 42467328);
  unsigned short* x_sa = (unsigned short*)(ws + 42516480);
  unsigned short* qkv = (unsigned short*)(ws + 50905088);
  unsigned short* vt_s = (unsigned short*)(ws + 76070912);
  unsigned short* sa = (unsigned short*)(ws + 84459520);
  unsigned short* xn = (unsigned short*)(ws + 42516480);
  unsigned short* qc = (unsigned short*)(ws + 50905088);
  unsigned short* kvc = (unsigned short*)(ws + 59293696);
  unsigned short* vt_c = (unsigned short*)(ws + 63488000);
  unsigned short* ca = (unsigned short*)(ws + 65585152);
  unsigned short* x_mlp = (unsigned short*)(ws + 42516480);
  unsigned short* gbuf = (unsigned short*)(ws + 50905088);
  unsigned short* ubuf = (unsigned short*)(ws + 84459520);

  // weight prep
  wtrans<<<dim3(96, 32), 256, 0, stream>>>(W_qkv, wt_qkv, 1024, 3072);
  wtrans<<<dim3(32, 32), 256, 0, stream>>>(W_sa, wt_sa, 1024, 1024);
  wtrans<<<dim3(32, 32), 256, 0, stream>>>(W_q, wt_q, 1024, 1024);
  wtrans<<<dim3(64, 24), 256, 0, stream>>>(W_kv, wt_kv, 768, 2048);
  wtrans<<<dim3(32, 32), 256, 0, stream>>>(W_ca, wt_ca, 1024, 1024);
  wtrans<<<dim3(128, 32), 256, 0, stream>>>(W_gate, wt_gate, 1024, 4096);
  wtrans<<<dim3(128, 32), 256, 0, stream>>>(W_up, wt_up, 1024, 4096);
  wtrans<<<dim3(32, 128), 256, 0, stream>>>(W_down, wt_down, 4096, 1024);
  f2bf_copy<<<768, 256, 0, stream>>>(audio, audio_bf, 786432);
  mods_kernel<<<dim3(24, 2), 256, 0, stream>>>(t_mod, adaW, adaB, mods);

  // self-attention block
  rmsnorm_mod<<<4096, 256, 0, stream>>>(x, norm1_w, mods, 0, 1024, x_sa);
  gemm_nt<0><<<dim3(32, 24), 256, 0, stream>>>(x_sa, wt_qkv, qkv, nullptr, nullptr, 4096, 3072, 1024);
  rope_qk<<<dim3(2048, 2), 256, 0, stream>>>(qkv, fcos, fsin);
  vtrans<<<dim3(32, 16, 2), 256, 0, stream>>>(qkv + 2048, vt_s, 3072, 6291456, 2048);
  attn2<<<dim3(32, 16, 2), 256, 0, stream>>>(qkv, 3072, 6291456, qkv + 1024, 3072, 6291456,
                                             vt_s, sa, 1024, 2097152, 2048);
  gemm_nt<1><<<dim3(32, 8), 256, 0, stream>>>(sa, wt_sa, x_res, x, mods + 2048, 4096, 1024, 1024);

  // cross-attention block
  rmsnorm_mod<<<4096, 256, 0, stream>>>(x_res, norm2_w, nullptr, 0, 0, xn);
  gemm_nt<0><<<dim3(32, 8), 256, 0, stream>>>(xn, wt_q, qc, nullptr, nullptr, 4096, 1024, 1024);
  gemm_nt<0><<<dim3(8, 16), 256, 0, stream>>>(audio_bf, wt_kv, kvc, nullptr, nullptr, 1024, 2048, 768);
  vtrans<<<dim3(8, 16, 2), 256, 0, stream>>>(kvc + 1024, vt_c, 2048, 1048576, 512);
  attn2<<<dim3(32, 16, 2), 256, 0, stream>>>(qc, 1024, 2097152, kvc, 2048, 1048576, vt_c, ca,
                                             1024, 2097152, 512);
  gemm_nt<1><<<dim3(32, 8), 256, 0, stream>>>(ca, wt_ca, x_res, x_res, nullptr, 4096, 1024, 1024);

  // MLP block
  rmsnorm_mod<<<4096, 256, 0, stream>>>(x_res, norm3_w, mods, 3072, 4096, x_mlp);
  gemm_nt<0><<<dim3(32, 32), 256, 0, stream>>>(x_mlp, wt_gate, gbuf, nullptr, nullptr, 4096, 4096, 1024);
  gemm_nt<0><<<dim3(32, 32), 256, 0, stream>>>(x_mlp, wt_up, ubuf, nullptr, nullptr, 4096, 4096, 1024);
  swiglu<<<8192, 256, 0, stream>>>(gbuf, ubuf, 16777216);
  gemm_nt<1><<<dim3(32, 8), 256, 0, stream>>>(gbuf, wt_down, x_res, x_res, mods + 5120, 4096, 1024, 4096);
}

// Round 3
// 763.146 us; speedup vs baseline: 1.6722x; 1.1537x over previous
//
#include <hip/hip_runtime.h>
#include <math.h>

// ---------- types ----------
typedef __attribute__((ext_vector_type(4))) float f32x4;
typedef __attribute__((ext_vector_type(4))) unsigned int u32x4;
typedef __attribute__((ext_vector_type(2))) unsigned int u32x2;
typedef __attribute__((ext_vector_type(8))) unsigned short u16x8;
typedef __attribute__((ext_vector_type(4))) unsigned short u16x4;
typedef __attribute__((ext_vector_type(8))) __bf16 bf16x8;

union F8 { u32x4 u; u16x8 us; bf16x8 v; };

__device__ __forceinline__ unsigned short f2bf(float f) {
  unsigned int u = __float_as_uint(f);
  u += 0x7fffu + ((u >> 16) & 1u);
  return (unsigned short)(u >> 16);
}
__device__ __forceinline__ float bf2f(unsigned short s) {
  return __uint_as_float(((unsigned int)s) << 16);
}

// ---------- weight transpose+convert: in fp32 (K x N) -> out bf16 (N x K) ----------
__global__ __launch_bounds__(256) void wtrans(const float* __restrict__ in,
                                              unsigned short* __restrict__ out,
                                              int K, int N) {
  __shared__ float tile[32][33];
  int tx = threadIdx.x & 31, ty = threadIdx.x >> 5;
  int n0 = blockIdx.x * 32, k0 = blockIdx.y * 32;
#pragma unroll
  for (int i = 0; i < 32; i += 8)
    tile[ty + i][tx] = in[(size_t)(k0 + ty + i) * N + n0 + tx];
  __syncthreads();
#pragma unroll
  for (int i = 0; i < 32; i += 8)
    out[(size_t)(n0 + ty + i) * K + k0 + tx] = f2bf(tile[tx][ty + i]);
}

// ---------- flat fp32 -> bf16 ----------
__global__ __launch_bounds__(256) void f2bf_copy(const float* __restrict__ in,
                                                 unsigned short* __restrict__ out, int n) {
  int i = (blockIdx.x * 256 + threadIdx.x) * 4;
  if (i < n) {
    f32x4 v = *(const f32x4*)(in + i);
    u16x4 o;
#pragma unroll
    for (int j = 0; j < 4; j++) o[j] = f2bf(v[j]);
    *(u16x4*)(out + i) = o;
  }
}

// ---------- mods = silu(t_mod) @ adaLN_W + adaLN_b ; (B x 6144) fp32 ----------
__global__ __launch_bounds__(256) void mods_kernel(const float* __restrict__ t_mod,
                                                   const float* __restrict__ W,
                                                   const float* __restrict__ bias,
                                                   float* __restrict__ mods) {
  int b = blockIdx.y;
  int j = blockIdx.x * 256 + threadIdx.x;
  __shared__ float a_s[1024];
  for (int i = threadIdx.x; i < 1024; i += 256) {
    float tv = t_mod[b * 1024 + i];
    a_s[i] = tv / (1.0f + expf(-tv));
  }
  __syncthreads();
  float acc = bias[j];
  for (int k = 0; k < 1024; k++) acc = fmaf(a_s[k], W[(size_t)k * 6144 + j], acc);
  mods[b * 6144 + j] = acc;
}

// ---------- rmsnorm (+ optional adaLN modulation), fp32 in -> bf16 out ----------
__global__ __launch_bounds__(256) void rmsnorm_mod(const float* __restrict__ x,
                                                   const float* __restrict__ w,
                                                   const float* mods, int shift_off,
                                                   int scale_off,
                                                   unsigned short* __restrict__ out) {
  int row = blockIdx.x;
  int b = row >> 11;
  const float* xr = x + (size_t)row * 1024;
  int t = threadIdx.x;
  f32x4 xv = *(const f32x4*)(xr + t * 4);
  float ss = xv[0] * xv[0] + xv[1] * xv[1] + xv[2] * xv[2] + xv[3] * xv[3];
#pragma unroll
  for (int off = 32; off >= 1; off >>= 1) ss += __shfl_xor(ss, off, 64);
  __shared__ float red[4];
  if ((t & 63) == 0) red[t >> 6] = ss;
  __syncthreads();
  float tot = red[0] + red[1] + red[2] + red[3];
  float rr = rsqrtf(tot * (1.0f / 1024.0f) + 1e-6f);
  f32x4 wv = *(const f32x4*)(w + t * 4);
  f32x4 scv = (f32x4)(0.0f), shv = (f32x4)(0.0f);
  if (mods) {
    scv = *(const f32x4*)(mods + b * 6144 + scale_off + t * 4);
    shv = *(const f32x4*)(mods + b * 6144 + shift_off + t * 4);
  }
  u16x4 ov;
#pragma unroll
  for (int j = 0; j < 4; j++) {
    float n = xv[j] * rr * wv[j];
    ov[j] = f2bf(n * (1.0f + scv[j]) + shv[j]);
  }
  *(u16x4*)(out + (size_t)row * 1024 + t * 4) = ov;
}

// ---------- GEMM: C(MxN) = A(MxK,bf16,lda) * Bt(NxK,bf16)^T ----------
template <int EPI>
__global__ __launch_bounds__(256) void gemm_nt(const unsigned short* __restrict__ A,
                                               const unsigned short* __restrict__ Bt,
                                               void* Cout, const float* res,
                                               const float* gate, int M, int N, int K,
                                               int lda) {
  __shared__ unsigned short As[128][40];
  __shared__ unsigned short Bs[128][40];
  int tid = threadIdx.x;
  int row0 = blockIdx.x * 128, col0 = blockIdx.y * 128;
  int wave = tid >> 6, lane = tid & 63;
  int wm = (wave & 1) * 64, wn = (wave >> 1) * 64;
  int mrow = lane & 15, grp = lane >> 4;
  f32x4 acc[4][4];
#pragma unroll
  for (int i = 0; i < 4; i++)
#pragma unroll
    for (int j = 0; j < 4; j++) acc[i][j] = (f32x4)(0.0f);

  int sr = tid >> 1, sk = (tid & 1) * 16;
  const unsigned short* pa = A + (size_t)(row0 + sr) * lda + sk;
  const unsigned short* pb = Bt + (size_t)(col0 + sr) * K + sk;

  for (int k0 = 0; k0 < K; k0 += 32) {
    __syncthreads();
    u32x4 a0 = *(const u32x4*)(pa + k0);
    u32x4 a1 = *(const u32x4*)(pa + k0 + 8);
    u32x4 b0 = *(const u32x4*)(pb + k0);
    u32x4 b1 = *(const u32x4*)(pb + k0 + 8);
    *(u32x4*)&As[sr][sk] = a0;
    *(u32x4*)&As[sr][sk + 8] = a1;
    *(u32x4*)&Bs[sr][sk] = b0;
    *(u32x4*)&Bs[sr][sk + 8] = b1;
    __syncthreads();
    bf16x8 af[4], bfr[4];
#pragma unroll
    for (int i = 0; i < 4; i++) {
      af[i] = *(const bf16x8*)&As[wm + i * 16 + mrow][grp * 8];
      bfr[i] = *(const bf16x8*)&Bs[wn + i * 16 + mrow][grp * 8];
    }
#pragma unroll
    for (int i = 0; i < 4; i++)
#pragma unroll
      for (int j = 0; j < 4; j++)
        acc[i][j] = __builtin_amdgcn_mfma_f32_16x16x32_bf16(af[i], bfr[j], acc[i][j], 0, 0, 0);
  }
#pragma unroll
  for (int i = 0; i < 4; i++) {
    int rbase = row0 + wm + i * 16 + grp * 4;
#pragma unroll
    for (int j = 0; j < 4; j++) {
      int col = col0 + wn + j * 16 + mrow;
      f32x4 a = acc[i][j];
#pragma unroll
      for (int r = 0; r < 4; r++) {
        size_t idx = (size_t)(rbase + r) * N + col;
        if (EPI == 0) {
          ((unsigned short*)Cout)[idx] = f2bf(a[r]);
        } else {
          float g = gate ? gate[((rbase + r) >> 11) * 6144 + col] : 1.0f;
          ((float*)Cout)[idx] = res[idx] + g * a[r];
        }
      }
    }
  }
}

// ---------- V transpose: in bf16 [b][l][..h..][d] -> out bf16 [b*H+h][d][l] ----------
__global__ __launch_bounds__(256) void vtrans(const unsigned short* __restrict__ in,
                                              unsigned short* __restrict__ out,
                                              int lstride, size_t bstride, int Lk) {
  int lt = blockIdx.x, h = blockIdx.y, b = blockIdx.z;
  __shared__ unsigned short tile[64][72];
  int t = threadIdx.x;
  int lrow = t >> 2, dp = (t & 3) * 16;
  const unsigned short* src =
      in + (size_t)b * bstride + (size_t)(lt * 64 + lrow) * lstride + h * 64 + dp;
  u32x4 v0 = *(const u32x4*)src;
  u32x4 v1 = *(const u32x4*)(src + 8);
  *(u32x4*)&tile[lrow][dp] = v0;
  *(u32x4*)&tile[lrow][dp + 8] = v1;
  __syncthreads();
  int d = t >> 2, lp = (t & 3) * 16;
  u16x8 t0, t1;
#pragma unroll
  for (int i = 0; i < 8; i++) {
    t0[i] = tile[lp + i][d];
    t1[i] = tile[lp + 8 + i][d];
  }
  unsigned short* dst = out + ((size_t)(b * 16 + h) * 64 + d) * Lk + lt * 64 + lp;
  *(u16x8*)dst = t0;
  *(u16x8*)(dst + 8) = t1;
}

// ---------- RoPE applied in-place to q,k planes of qkv [b][l][3][16][64] ----------
__global__ __launch_bounds__(256) void rope_qk(unsigned short* __restrict__ qkv,
                                               const float* __restrict__ fcos,
                                               const float* __restrict__ fsin) {
  int l = blockIdx.x, b = blockIdx.y;
  int t = threadIdx.x;
  int plane = t >> 7, rem = t & 127;
  int hh = rem >> 3, off = (rem & 7) * 8;
  unsigned short* p = qkv + (((size_t)(b * 2048 + l) * 3 + plane) * 16 + hh) * 64 + off;
  F8 f;
  f.u = *(const u32x4*)p;
  f32x4 c = *(const f32x4*)(fcos + l * 32 + off / 2);
  f32x4 s = *(const f32x4*)(fsin + l * 32 + off / 2);
  u16x8 o;
#pragma unroll
  for (int j = 0; j < 4; j++) {
    float xr = bf2f(f.us[2 * j]), xi = bf2f(f.us[2 * j + 1]);
    o[2 * j] = f2bf(xr * c[j] - xi * s[j]);
    o[2 * j + 1] = f2bf(xr * s[j] + xi * c[j]);
  }
  *(u16x8*)p = o;
}

// ---------- flash attention v3: S^T softmax, ones-column l, 128-key tiles ----------
__global__ __launch_bounds__(256) void attn3(const unsigned short* __restrict__ qb, int q_ls,
                                             size_t q_bs, const unsigned short* __restrict__ kb,
                                             int k_ls, size_t k_bs,
                                             const unsigned short* __restrict__ vt,
                                             unsigned short* __restrict__ ob, int o_ls,
                                             size_t o_bs, int Lk) {
  int qt = blockIdx.x, h = blockIdx.y, b = blockIdx.z;
  int tid = threadIdx.x;
  int w = tid >> 6, lane = tid & 63;
  int mrow = lane & 15, grp = lane >> 4;
  int q0 = qt * 64 + w * 16;
  __shared__ unsigned short Ks[128][72];
  __shared__ unsigned short Vs[80][136];
  __shared__ unsigned short Ps[4][16][136];
  __shared__ float alf[4][16];

  // Q fragments (B operand for S^T): lane mrow -> query q0+mrow
  const unsigned short* qp =
      qb + (size_t)b * q_bs + (size_t)(q0 + mrow) * q_ls + h * 64 + grp * 8;
  bf16x8 qf0, qf1;
  {
    F8 f;
    f.u = *(const u32x4*)qp;
    qf0 = f.v;
    f.u = *(const u32x4*)(qp + 32);
    qf1 = f.v;
  }
  const unsigned short* kbb = kb + (size_t)b * k_bs + h * 64;
  const unsigned short* vtb = vt + (size_t)(b * 16 + h) * 64 * Lk;

  // ones row 64 (l accumulator), zeros rows 65..79 — written once
  {
    int r = 64 + (tid >> 4), c = (tid & 15) * 8;
    unsigned short val = (tid >> 4) == 0 ? (unsigned short)0x3F80 : (unsigned short)0;
    u16x8 vv;
#pragma unroll
    for (int j = 0; j < 8; j++) vv[j] = val;
    *(u16x8*)&Vs[r][c] = vv;
  }

  const float K2 = 0.125f * 1.4426950408889634f;  // scale * log2(e)
  float m_run = -INFINITY;                        // per lane: query q0+mrow
  f32x4 o[5];
#pragma unroll
  for (int nt = 0; nt < 5; nt++) o[nt] = (f32x4)(0.0f);

  int krow = tid >> 3, kcol = (tid & 7) * 8;
  int vrow = tid >> 4, vcol = (tid & 15) * 8;
  u32x4 kreg[4], vreg[4];
#pragma unroll
  for (int i = 0; i < 4; i++) {
    kreg[i] = *(const u32x4*)(kbb + (size_t)(krow + i * 32) * k_ls + kcol);
    vreg[i] = *(const u32x4*)(vtb + (size_t)(vrow + i * 16) * Lk + vcol);
  }

  for (int k0 = 0; k0 < Lk; k0 += 128) {
    __syncthreads();
#pragma unroll
    for (int i = 0; i < 4; i++) {
      *(u32x4*)&Ks[krow + i * 32][kcol] = kreg[i];
      *(u32x4*)&Vs[vrow + i * 16][vcol] = vreg[i];
    }
    __syncthreads();
    int kn = k0 + 128;
    if (kn < Lk) {
#pragma unroll
      for (int i = 0; i < 4; i++) {
        kreg[i] = *(const u32x4*)(kbb + (size_t)(kn + krow + i * 32) * k_ls + kcol);
        vreg[i] = *(const u32x4*)(vtb + (size_t)(vrow + i * 16) * Lk + kn + vcol);
      }
    }
    // S^T: sc[si] rows = keys si*16+grp*4+r, col = query mrow
    f32x4 sc[8];
#pragma unroll
    for (int si = 0; si < 8; si++) {
      F8 kf0, kf1;
      kf0.u = *(const u32x4*)&Ks[si * 16 + mrow][grp * 8];
      kf1.u = *(const u32x4*)&Ks[si * 16 + mrow][32 + grp * 8];
      f32x4 s = (f32x4)(0.0f);
      s = __builtin_amdgcn_mfma_f32_16x16x32_bf16(kf0.v, qf0, s, 0, 0, 0);
      s = __builtin_amdgcn_mfma_f32_16x16x32_bf16(kf1.v, qf1, s, 0, 0, 0);
      sc[si] = s;
    }
    // per-lane max over 32 scores (all same query), then reduce over grp
    f32x4 mv = sc[0];
#pragma unroll
    for (int si = 1; si < 8; si++) {
#pragma unroll
      for (int r = 0; r < 4; r++) mv[r] = fmaxf(mv[r], sc[si][r]);
    }
    float v = fmaxf(fmaxf(mv[0], mv[1]), fmaxf(mv[2], mv[3])) * K2;
    v = fmaxf(v, __shfl_xor(v, 16, 64));
    v = fmaxf(v, __shfl_xor(v, 32, 64));
    float mnew = fmaxf(m_run, v);
    float alpha = __builtin_amdgcn_exp2f(m_run - mnew);
    m_run = mnew;
    if (lane < 16) alf[w][lane] = alpha;
    float negm = -mnew;
    // p = exp2(s*K2 - mnew), truncate to bf16, packed b64 stores (wave-local Ps)
#pragma unroll
    for (int si = 0; si < 8; si++) {
      float p0 = __builtin_amdgcn_exp2f(fmaf(sc[si][0], K2, negm));
      float p1 = __builtin_amdgcn_exp2f(fmaf(sc[si][1], K2, negm));
      float p2 = __builtin_amdgcn_exp2f(fmaf(sc[si][2], K2, negm));
      float p3 = __builtin_amdgcn_exp2f(fmaf(sc[si][3], K2, negm));
      u32x2 pk;
      pk[0] = (__float_as_uint(p0) >> 16) | (__float_as_uint(p1) & 0xFFFF0000u);
      pk[1] = (__float_as_uint(p2) >> 16) | (__float_as_uint(p3) & 0xFFFF0000u);
      *(u32x2*)&Ps[w][mrow][si * 16 + grp * 4] = pk;
    }
    // rescale o by alpha (fetched in C-layout via per-wave LDS; wave-internal, no barrier)
    f32x4 av = *(const f32x4*)&alf[w][grp * 4];
#pragma unroll
    for (int nt = 0; nt < 5; nt++) {
#pragma unroll
      for (int r = 0; r < 4; r++) o[nt][r] *= av[r];
    }
    // PV: A = P fragments (reused across nt), B = V^T rows (+ ones row for l)
    bf16x8 pf[4];
#pragma unroll
    for (int kk = 0; kk < 4; kk++) {
      F8 f;
      f.u = *(const u32x4*)&Ps[w][mrow][kk * 32 + grp * 8];
      pf[kk] = f.v;
    }
#pragma unroll
    for (int nt = 0; nt < 5; nt++) {
#pragma unroll
      for (int kk = 0; kk < 4; kk++) {
        F8 vf;
        vf.u = *(const u32x4*)&Vs[nt * 16 + mrow][kk * 32 + grp * 8];
        o[nt] = __builtin_amdgcn_mfma_f32_16x16x32_bf16(pf[kk], vf.v, o[nt], 0, 0, 0);
      }
    }
  }
  // epilogue: l lives in o[4], col 0 (lanes mrow==0); other cols are exact zeros
  float inv[4];
#pragma unroll
  for (int r = 0; r < 4; r++) {
    float lv = __shfl(o[4][r], lane & 48, 64);
    inv[r] = 1.0f / lv;
  }
  unsigned short* op = ob + (size_t)b * o_bs + h * 64;
#pragma unroll
  for (int nt = 0; nt < 4; nt++)
#pragma unroll
    for (int r = 0; r < 4; r++) {
      int row = q0 + grp * 4 + r;
      op[(size_t)row * o_ls + nt * 16 + mrow] = f2bf(o[nt][r] * inv[r]);
    }
}

// ---------- swiglu on fused [m][8192] buffer: cols 0..4095 = gate, 4096.. = up; in-place ----------
__global__ __launch_bounds__(256) void swiglu2(unsigned short* __restrict__ gu) {
  int m = blockIdx.y;
  int c = (blockIdx.x * 256 + threadIdx.x) * 8;
  unsigned short* g = gu + (size_t)m * 8192 + c;
  const unsigned short* u = g + 4096;
  F8 gv, uv;
  gv.u = *(const u32x4*)g;
  uv.u = *(const u32x4*)u;
  u16x8 h;
#pragma unroll
  for (int j = 0; j < 8; j++) {
    float gf = bf2f(gv.us[j]), uf = bf2f(uv.us[j]);
    h[j] = f2bf(gf / (1.0f + expf(-gf)) * uf);
  }
  *(u16x8*)g = h;
}

// ---------- launcher ----------
extern "C" void kernel_launch(void* const* d_in, const int* in_sizes, int n_in, void* d_out,
                              int out_size, void* d_ws, size_t ws_size, hipStream_t stream) {
  const float* x = (const float*)d_in[0];
  const float* t_mod = (const float*)d_in[1];
  const float* audio = (const float*)d_in[2];
  const float* fcos = (const float*)d_in[3];
  const float* fsin = (const float*)d_in[4];
  const float* norm1_w = (const float*)d_in[5];
  const float* norm2_w = (const float*)d_in[6];
  const float* norm3_w = (const float*)d_in[7];
  const float* W_qkv = (const float*)d_in[8];
  const float* W_sa = (const float*)d_in[9];
  const float* W_q = (const float*)d_in[10];
  const float* W_kv = (const float*)d_in[11];
  const float* W_ca = (const float*)d_in[12];
  const float* W_gate = (const float*)d_in[13];
  const float* W_up = (const float*)d_in[14];
  const float* W_down = (const float*)d_in[15];
  const float* adaW = (const float*)d_in[16];
  const float* adaB = (const float*)d_in[17];

  char* ws = (char*)d_ws;
  float* x_res = (float*)d_out;  // residual stream lives in d_out (fp32)

  unsigned short* wt_qkv = (unsigned short*)(ws + 0);
  unsigned short* wt_sa = (unsigned short*)(ws + 6291456);
  unsigned short* wt_q = (unsigned short*)(ws + 8388608);
  unsigned short* wt_kv = (unsigned short*)(ws + 10485760);
  unsigned short* wt_ca = (unsigned short*)(ws + 13631488);
  unsigned short* wt_gate = (unsigned short*)(ws + 15728640);  // + wt_up contiguous after
  unsigned short* wt_down = (unsigned short*)(ws + 32505856);
  unsigned short* audio_bf = (unsigned short*)(ws + 40894464);
  float* mods = (float*)(ws + 42467328);
  unsigned short* x_sa = (unsigned short*)(ws + 42516480);
  unsigned short* qkv = (unsigned short*)(ws + 50905088);
  unsigned short* vt_s = (unsigned short*)(ws + 76070912);
  unsigned short* sa = (unsigned short*)(ws + 84459520);
  unsigned short* xn = (unsigned short*)(ws + 42516480);
  unsigned short* qc = (unsigned short*)(ws + 50905088);
  unsigned short* kvc = (unsigned short*)(ws + 59293696);
  unsigned short* vt_c = (unsigned short*)(ws + 63488000);
  unsigned short* ca = (unsigned short*)(ws + 65585152);
  unsigned short* x_mlp = (unsigned short*)(ws + 42516480);
  unsigned short* gubuf = (unsigned short*)(ws + 50905088);  // 4096 x 8192 bf16 = 64MB

  // weight prep
  wtrans<<<dim3(96, 32), 256, 0, stream>>>(W_qkv, wt_qkv, 1024, 3072);
  wtrans<<<dim3(32, 32), 256, 0, stream>>>(W_sa, wt_sa, 1024, 1024);
  wtrans<<<dim3(32, 32), 256, 0, stream>>>(W_q, wt_q, 1024, 1024);
  wtrans<<<dim3(64, 24), 256, 0, stream>>>(W_kv, wt_kv, 768, 2048);
  wtrans<<<dim3(32, 32), 256, 0, stream>>>(W_ca, wt_ca, 1024, 1024);
  wtrans<<<dim3(128, 32), 256, 0, stream>>>(W_gate, wt_gate, 1024, 4096);
  wtrans<<<dim3(128, 32), 256, 0, stream>>>(W_up, wt_gate + 4194304, 1024, 4096);
  wtrans<<<dim3(32, 128), 256, 0, stream>>>(W_down, wt_down, 4096, 1024);
  f2bf_copy<<<768, 256, 0, stream>>>(audio, audio_bf, 786432);
  mods_kernel<<<dim3(24, 2), 256, 0, stream>>>(t_mod, adaW, adaB, mods);

  // self-attention block
  rmsnorm_mod<<<4096, 256, 0, stream>>>(x, norm1_w, mods, 0, 1024, x_sa);
  gemm_nt<0><<<dim3(32, 24), 256, 0, stream>>>(x_sa, wt_qkv, qkv, nullptr, nullptr, 4096, 3072, 1024, 1024);
  rope_qk<<<dim3(2048, 2), 256, 0, stream>>>(qkv, fcos, fsin);
  vtrans<<<dim3(32, 16, 2), 256, 0, stream>>>(qkv + 2048, vt_s, 3072, 6291456, 2048);
  attn3<<<dim3(32, 16, 2), 256, 0, stream>>>(qkv, 3072, 6291456, qkv + 1024, 3072, 6291456,
                                             vt_s, sa, 1024, 2097152, 2048);
  gemm_nt<1><<<dim3(32, 8), 256, 0, stream>>>(sa, wt_sa, x_res, x, mods + 2048, 4096, 1024, 1024, 1024);

  // cross-attention block
  rmsnorm_mod<<<4096, 256, 0, stream>>>(x_res, norm2_w, nullptr, 0, 0, xn);
  gemm_nt<0><<<dim3(32, 8), 256, 0, stream>>>(xn, wt_q, qc, nullptr, nullptr, 4096, 1024, 1024, 1024);
  gemm_nt<0><<<dim3(8, 16), 256, 0, stream>>>(audio_bf, wt_kv, kvc, nullptr, nullptr, 1024, 2048, 768, 768);
  vtrans<<<dim3(8, 16, 2), 256, 0, stream>>>(kvc + 1024, vt_c, 2048, 1048576, 512);
  attn3<<<dim3(32, 16, 2), 256, 0, stream>>>(qc, 1024, 2097152, kvc, 2048, 1048576, vt_c, ca,
                                             1024, 2097152, 512);
  gemm_nt<1><<<dim3(32, 8), 256, 0, stream>>>(ca, wt_ca, x_res, x_res, nullptr, 4096, 1024, 1024, 1024);

  // MLP block (gate+up fused: weights contiguous, N=8192)
  rmsnorm_mod<<<4096, 256, 0, stream>>>(x_res, norm3_w, mods, 3072, 4096, x_mlp);
  gemm_nt<0><<<dim3(32, 64), 256, 0, stream>>>(x_mlp, wt_gate, gubuf, nullptr, nullptr, 4096, 8192, 1024, 1024);
  swiglu2<<<dim3(2, 4096), 256, 0, stream>>>(gubuf);
  gemm_nt<1><<<dim3(32, 8), 256, 0, stream>>>(gubuf, wt_down, x_res, x_res, mods + 5120, 4096, 1024, 4096, 8192);
}

// Round 4
// 684.373 us; speedup vs baseline: 1.8647x; 1.1151x over previous
//
#include <hip/hip_runtime.h>
#include <math.h>

// ---------- types ----------
typedef __attribute__((ext_vector_type(4))) float f32x4;
typedef __attribute__((ext_vector_type(4))) unsigned int u32x4;
typedef __attribute__((ext_vector_type(2))) unsigned int u32x2;
typedef __attribute__((ext_vector_type(8))) unsigned short u16x8;
typedef __attribute__((ext_vector_type(4))) unsigned short u16x4;
typedef __attribute__((ext_vector_type(8))) __bf16 bf16x8;

union F8 { u32x4 u; u16x8 us; bf16x8 v; };

__device__ __forceinline__ unsigned short f2bf(float f) {
  unsigned int u = __float_as_uint(f);
  u += 0x7fffu + ((u >> 16) & 1u);
  return (unsigned short)(u >> 16);
}
__device__ __forceinline__ float bf2f(unsigned short s) {
  return __uint_as_float(((unsigned int)s) << 16);
}

// async global->LDS, 16B per lane; lds dest = wave-uniform base + lane*16
__device__ __forceinline__ void ldsload16(const void* g, void* l) {
  __builtin_amdgcn_global_load_lds((const __attribute__((address_space(1))) unsigned int*)g,
                                   (__attribute__((address_space(3))) unsigned int*)l, 16, 0, 0);
}

// ---------- weight transpose+convert: in fp32 (K x N) -> out bf16 (N x K) ----------
__global__ __launch_bounds__(256) void wtrans(const float* __restrict__ in,
                                              unsigned short* __restrict__ out,
                                              int K, int N) {
  __shared__ float tile[32][33];
  int tx = threadIdx.x & 31, ty = threadIdx.x >> 5;
  int n0 = blockIdx.x * 32, k0 = blockIdx.y * 32;
#pragma unroll
  for (int i = 0; i < 32; i += 8)
    tile[ty + i][tx] = in[(size_t)(k0 + ty + i) * N + n0 + tx];
  __syncthreads();
#pragma unroll
  for (int i = 0; i < 32; i += 8)
    out[(size_t)(n0 + ty + i) * K + k0 + tx] = f2bf(tile[tx][ty + i]);
}

// ---------- flat fp32 -> bf16 ----------
__global__ __launch_bounds__(256) void f2bf_copy(const float* __restrict__ in,
                                                 unsigned short* __restrict__ out, int n) {
  int i = (blockIdx.x * 256 + threadIdx.x) * 4;
  if (i < n) {
    f32x4 v = *(const f32x4*)(in + i);
    u16x4 o;
#pragma unroll
    for (int j = 0; j < 4; j++) o[j] = f2bf(v[j]);
    *(u16x4*)(out + i) = o;
  }
}

// ---------- mods = silu(t_mod) @ adaLN_W + adaLN_b ; (B x 6144) fp32 ----------
__global__ __launch_bounds__(256) void mods_kernel(const float* __restrict__ t_mod,
                                                   const float* __restrict__ W,
                                                   const float* __restrict__ bias,
                                                   float* __restrict__ mods) {
  int b = blockIdx.y;
  int j = blockIdx.x * 256 + threadIdx.x;
  __shared__ float a_s[1024];
  for (int i = threadIdx.x; i < 1024; i += 256) {
    float tv = t_mod[b * 1024 + i];
    a_s[i] = tv / (1.0f + expf(-tv));
  }
  __syncthreads();
  float acc = bias[j];
  for (int k = 0; k < 1024; k++) acc = fmaf(a_s[k], W[(size_t)k * 6144 + j], acc);
  mods[b * 6144 + j] = acc;
}

// ---------- rmsnorm (+ optional adaLN modulation), fp32 in -> bf16 out ----------
__global__ __launch_bounds__(256) void rmsnorm_mod(const float* __restrict__ x,
                                                   const float* __restrict__ w,
                                                   const float* mods, int shift_off,
                                                   int scale_off,
                                                   unsigned short* __restrict__ out) {
  int row = blockIdx.x;
  int b = row >> 11;
  const float* xr = x + (size_t)row * 1024;
  int t = threadIdx.x;
  f32x4 xv = *(const f32x4*)(xr + t * 4);
  float ss = xv[0] * xv[0] + xv[1] * xv[1] + xv[2] * xv[2] + xv[3] * xv[3];
#pragma unroll
  for (int off = 32; off >= 1; off >>= 1) ss += __shfl_xor(ss, off, 64);
  __shared__ float red[4];
  if ((t & 63) == 0) red[t >> 6] = ss;
  __syncthreads();
  float tot = red[0] + red[1] + red[2] + red[3];
  float rr = rsqrtf(tot * (1.0f / 1024.0f) + 1e-6f);
  f32x4 wv = *(const f32x4*)(w + t * 4);
  f32x4 scv = (f32x4)(0.0f), shv = (f32x4)(0.0f);
  if (mods) {
    scv = *(const f32x4*)(mods + b * 6144 + scale_off + t * 4);
    shv = *(const f32x4*)(mods + b * 6144 + shift_off + t * 4);
  }
  u16x4 ov;
#pragma unroll
  for (int j = 0; j < 4; j++) {
    float n = xv[j] * rr * wv[j];
    ov[j] = f2bf(n * (1.0f + scv[j]) + shv[j]);
  }
  *(u16x4*)(out + (size_t)row * 1024 + t * 4) = ov;
}

// ---------- GEMM: C(Mx N) = A(MxK,bf16,lda) * Bt(NxK,bf16)^T ----------
// M-tile 128, N-tile NT (128 or 64). Staging via global_load_lds width 16.
// EPI 0: store bf16. EPI 1: fp32 out = res + gate*acc (gate row = m>>11, stride 6144)
template <int EPI, int NT>
__global__ __launch_bounds__(256) void gemm_nt(const unsigned short* __restrict__ A,
                                               const unsigned short* __restrict__ Bt,
                                               void* Cout, const float* res,
                                               const float* gate, int M, int N, int K,
                                               int lda) {
  constexpr int JT = NT / 32;  // j-tiles per wave (4 or 2)
  __shared__ unsigned short As[128 * 32];
  __shared__ unsigned short Bs[NT * 32];
  int tid = threadIdx.x;
  int row0 = blockIdx.x * 128, col0 = blockIdx.y * NT;
  int wave = tid >> 6, lane = tid & 63;
  int wm = (wave & 1) * 64, wn = (wave >> 1) * (NT / 2);
  int mrow = lane & 15, grp = lane >> 4;
  f32x4 acc[4][JT];
#pragma unroll
  for (int i = 0; i < 4; i++)
#pragma unroll
    for (int j = 0; j < JT; j++) acc[i][j] = (f32x4)(0.0f);

  // staging coords: per instr a wave covers 16 rows x 32 k (64 lanes x 8 elem)
  int sr = lane >> 2, skq = (lane & 3) * 8;
  const unsigned short* paG = A + (size_t)(row0 + wave * 32 + sr) * lda + skq;
  unsigned short* lA = &As[wave * 32 * 32];
  const unsigned short* pbG;
  unsigned short* lB;
  if (NT == 128) {
    pbG = Bt + (size_t)(col0 + wave * 32 + sr) * K + skq;
    lB = &Bs[wave * 32 * 32];
  } else {
    pbG = Bt + (size_t)(col0 + wave * 16 + sr) * K + skq;
    lB = &Bs[wave * 16 * 32];
  }

  for (int k0 = 0; k0 < K; k0 += 32) {
    __syncthreads();
    ldsload16(paG + k0, lA);
    ldsload16(paG + k0 + 16 * (size_t)lda, lA + 16 * 32);
    ldsload16(pbG + k0, lB);
    if (NT == 128) ldsload16(pbG + k0 + 16 * (size_t)K, lB + 16 * 32);
    __syncthreads();
    bf16x8 af[4], bfr[JT];
#pragma unroll
    for (int i = 0; i < 4; i++)
      af[i] = *(const bf16x8*)&As[(wm + i * 16 + mrow) * 32 + grp * 8];
#pragma unroll
    for (int j = 0; j < JT; j++)
      bfr[j] = *(const bf16x8*)&Bs[(wn + j * 16 + mrow) * 32 + grp * 8];
#pragma unroll
    for (int i = 0; i < 4; i++)
#pragma unroll
      for (int j = 0; j < JT; j++)
        acc[i][j] = __builtin_amdgcn_mfma_f32_16x16x32_bf16(af[i], bfr[j], acc[i][j], 0, 0, 0);
  }
#pragma unroll
  for (int i = 0; i < 4; i++) {
    int rbase = row0 + wm + i * 16 + grp * 4;
#pragma unroll
    for (int j = 0; j < JT; j++) {
      int col = col0 + wn + j * 16 + mrow;
      f32x4 a = acc[i][j];
#pragma unroll
      for (int r = 0; r < 4; r++) {
        size_t idx = (size_t)(rbase + r) * N + col;
        if (EPI == 0) {
          ((unsigned short*)Cout)[idx] = f2bf(a[r]);
        } else {
          float g = gate ? gate[((rbase + r) >> 11) * 6144 + col] : 1.0f;
          ((float*)Cout)[idx] = res[idx] + g * a[r];
        }
      }
    }
  }
}

// ---------- V transpose: in bf16 [b][l][..h..][d] -> out bf16 [b*H+h][d][l] ----------
__global__ __launch_bounds__(256) void vtrans(const unsigned short* __restrict__ in,
                                              unsigned short* __restrict__ out,
                                              int lstride, size_t bstride, int Lk) {
  int lt = blockIdx.x, h = blockIdx.y, b = blockIdx.z;
  __shared__ unsigned short tile[64][72];
  int t = threadIdx.x;
  int lrow = t >> 2, dp = (t & 3) * 16;
  const unsigned short* src =
      in + (size_t)b * bstride + (size_t)(lt * 64 + lrow) * lstride + h * 64 + dp;
  u32x4 v0 = *(const u32x4*)src;
  u32x4 v1 = *(const u32x4*)(src + 8);
  *(u32x4*)&tile[lrow][dp] = v0;
  *(u32x4*)&tile[lrow][dp + 8] = v1;
  __syncthreads();
  int d = t >> 2, lp = (t & 3) * 16;
  u16x8 t0, t1;
#pragma unroll
  for (int i = 0; i < 8; i++) {
    t0[i] = tile[lp + i][d];
    t1[i] = tile[lp + 8 + i][d];
  }
  unsigned short* dst = out + ((size_t)(b * 16 + h) * 64 + d) * Lk + lt * 64 + lp;
  *(u16x8*)dst = t0;
  *(u16x8*)(dst + 8) = t1;
}

// ---------- RoPE applied in-place to q,k planes of qkv [b][l][3][16][64] ----------
__global__ __launch_bounds__(256) void rope_qk(unsigned short* __restrict__ qkv,
                                               const float* __restrict__ fcos,
                                               const float* __restrict__ fsin) {
  int l = blockIdx.x, b = blockIdx.y;
  int t = threadIdx.x;
  int plane = t >> 7, rem = t & 127;
  int hh = rem >> 3, off = (rem & 7) * 8;
  unsigned short* p = qkv + (((size_t)(b * 2048 + l) * 3 + plane) * 16 + hh) * 64 + off;
  F8 f;
  f.u = *(const u32x4*)p;
  f32x4 c = *(const f32x4*)(fcos + l * 32 + off / 2);
  f32x4 s = *(const f32x4*)(fsin + l * 32 + off / 2);
  u16x8 o;
#pragma unroll
  for (int j = 0; j < 4; j++) {
    float xr = bf2f(f.us[2 * j]), xi = bf2f(f.us[2 * j + 1]);
    o[2 * j] = f2bf(xr * c[j] - xi * s[j]);
    o[2 * j + 1] = f2bf(xr * s[j] + xi * c[j]);
  }
  *(u16x8*)p = o;
}

// ---------- flash attention v3: S^T softmax, ones-column l, 128-key tiles ----------
__global__ __launch_bounds__(256) void attn3(const unsigned short* __restrict__ qb, int q_ls,
                                             size_t q_bs, const unsigned short* __restrict__ kb,
                                             int k_ls, size_t k_bs,
                                             const unsigned short* __restrict__ vt,
                                             unsigned short* __restrict__ ob, int o_ls,
                                             size_t o_bs, int Lk) {
  int qt = blockIdx.x, h = blockIdx.y, b = blockIdx.z;
  int tid = threadIdx.x;
  int w = tid >> 6, lane = tid & 63;
  int mrow = lane & 15, grp = lane >> 4;
  int q0 = qt * 64 + w * 16;
  __shared__ unsigned short Ks[128][72];
  __shared__ unsigned short Vs[80][136];
  __shared__ unsigned short Ps[4][16][136];
  __shared__ float alf[4][16];

  const unsigned short* qp =
      qb + (size_t)b * q_bs + (size_t)(q0 + mrow) * q_ls + h * 64 + grp * 8;
  bf16x8 qf0, qf1;
  {
    F8 f;
    f.u = *(const u32x4*)qp;
    qf0 = f.v;
    f.u = *(const u32x4*)(qp + 32);
    qf1 = f.v;
  }
  const unsigned short* kbb = kb + (size_t)b * k_bs + h * 64;
  const unsigned short* vtb = vt + (size_t)(b * 16 + h) * 64 * Lk;

  {
    int r = 64 + (tid >> 4), c = (tid & 15) * 8;
    unsigned short val = (tid >> 4) == 0 ? (unsigned short)0x3F80 : (unsigned short)0;
    u16x8 vv;
#pragma unroll
    for (int j = 0; j < 8; j++) vv[j] = val;
    *(u16x8*)&Vs[r][c] = vv;
  }

  const float K2 = 0.125f * 1.4426950408889634f;
  float m_run = -INFINITY;
  f32x4 o[5];
#pragma unroll
  for (int nt = 0; nt < 5; nt++) o[nt] = (f32x4)(0.0f);

  int krow = tid >> 3, kcol = (tid & 7) * 8;
  int vrow = tid >> 4, vcol = (tid & 15) * 8;
  u32x4 kreg[4], vreg[4];
#pragma unroll
  for (int i = 0; i < 4; i++) {
    kreg[i] = *(const u32x4*)(kbb + (size_t)(krow + i * 32) * k_ls + kcol);
    vreg[i] = *(const u32x4*)(vtb + (size_t)(vrow + i * 16) * Lk + vcol);
  }

  for (int k0 = 0; k0 < Lk; k0 += 128) {
    __syncthreads();
#pragma unroll
    for (int i = 0; i < 4; i++) {
      *(u32x4*)&Ks[krow + i * 32][kcol] = kreg[i];
      *(u32x4*)&Vs[vrow + i * 16][vcol] = vreg[i];
    }
    __syncthreads();
    int kn = k0 + 128;
    if (kn < Lk) {
#pragma unroll
      for (int i = 0; i < 4; i++) {
        kreg[i] = *(const u32x4*)(kbb + (size_t)(kn + krow + i * 32) * k_ls + kcol);
        vreg[i] = *(const u32x4*)(vtb + (size_t)(vrow + i * 16) * Lk + kn + vcol);
      }
    }
    f32x4 sc[8];
#pragma unroll
    for (int si = 0; si < 8; si++) {
      F8 kf0, kf1;
      kf0.u = *(const u32x4*)&Ks[si * 16 + mrow][grp * 8];
      kf1.u = *(const u32x4*)&Ks[si * 16 + mrow][32 + grp * 8];
      f32x4 s = (f32x4)(0.0f);
      s = __builtin_amdgcn_mfma_f32_16x16x32_bf16(kf0.v, qf0, s, 0, 0, 0);
      s = __builtin_amdgcn_mfma_f32_16x16x32_bf16(kf1.v, qf1, s, 0, 0, 0);
      sc[si] = s;
    }
    f32x4 mv = sc[0];
#pragma unroll
    for (int si = 1; si < 8; si++) {
#pragma unroll
      for (int r = 0; r < 4; r++) mv[r] = fmaxf(mv[r], sc[si][r]);
    }
    float v = fmaxf(fmaxf(mv[0], mv[1]), fmaxf(mv[2], mv[3])) * K2;
    v = fmaxf(v, __shfl_xor(v, 16, 64));
    v = fmaxf(v, __shfl_xor(v, 32, 64));
    float mnew = fmaxf(m_run, v);
    float alpha = __builtin_amdgcn_exp2f(m_run - mnew);
    m_run = mnew;
    if (lane < 16) alf[w][lane] = alpha;
    float negm = -mnew;
#pragma unroll
    for (int si = 0; si < 8; si++) {
      float p0 = __builtin_amdgcn_exp2f(fmaf(sc[si][0], K2, negm));
      float p1 = __builtin_amdgcn_exp2f(fmaf(sc[si][1], K2, negm));
      float p2 = __builtin_amdgcn_exp2f(fmaf(sc[si][2], K2, negm));
      float p3 = __builtin_amdgcn_exp2f(fmaf(sc[si][3], K2, negm));
      u32x2 pk;
      pk[0] = (__float_as_uint(p0) >> 16) | (__float_as_uint(p1) & 0xFFFF0000u);
      pk[1] = (__float_as_uint(p2) >> 16) | (__float_as_uint(p3) & 0xFFFF0000u);
      *(u32x2*)&Ps[w][mrow][si * 16 + grp * 4] = pk;
    }
    f32x4 av = *(const f32x4*)&alf[w][grp * 4];
#pragma unroll
    for (int nt = 0; nt < 5; nt++) {
#pragma unroll
      for (int r = 0; r < 4; r++) o[nt][r] *= av[r];
    }
    bf16x8 pf[4];
#pragma unroll
    for (int kk = 0; kk < 4; kk++) {
      F8 f;
      f.u = *(const u32x4*)&Ps[w][mrow][kk * 32 + grp * 8];
      pf[kk] = f.v;
    }
#pragma unroll
    for (int nt = 0; nt < 5; nt++) {
#pragma unroll
      for (int kk = 0; kk < 4; kk++) {
        F8 vf;
        vf.u = *(const u32x4*)&Vs[nt * 16 + mrow][kk * 32 + grp * 8];
        o[nt] = __builtin_amdgcn_mfma_f32_16x16x32_bf16(pf[kk], vf.v, o[nt], 0, 0, 0);
      }
    }
  }
  float inv[4];
#pragma unroll
  for (int r = 0; r < 4; r++) {
    float lv = __shfl(o[4][r], lane & 48, 64);
    inv[r] = 1.0f / lv;
  }
  unsigned short* op = ob + (size_t)b * o_bs + h * 64;
#pragma unroll
  for (int nt = 0; nt < 4; nt++)
#pragma unroll
    for (int r = 0; r < 4; r++) {
      int row = q0 + grp * 4 + r;
      op[(size_t)row * o_ls + nt * 16 + mrow] = f2bf(o[nt][r] * inv[r]);
    }
}

// ---------- swiglu on fused [m][8192] buffer: cols 0..4095 = gate, 4096.. = up; in-place ----------
__global__ __launch_bounds__(256) void swiglu2(unsigned short* __restrict__ gu) {
  int m = blockIdx.y;
  int c = (blockIdx.x * 256 + threadIdx.x) * 8;
  unsigned short* g = gu + (size_t)m * 8192 + c;
  const unsigned short* u = g + 4096;
  F8 gv, uv;
  gv.u = *(const u32x4*)g;
  uv.u = *(const u32x4*)u;
  u16x8 h;
#pragma unroll
  for (int j = 0; j < 8; j++) {
    float gf = bf2f(gv.us[j]), uf = bf2f(uv.us[j]);
    h[j] = f2bf(gf / (1.0f + expf(-gf)) * uf);
  }
  *(u16x8*)g = h;
}

// ---------- launcher ----------
extern "C" void kernel_launch(void* const* d_in, const int* in_sizes, int n_in, void* d_out,
                              int out_size, void* d_ws, size_t ws_size, hipStream_t stream) {
  const float* x = (const float*)d_in[0];
  const float* t_mod = (const float*)d_in[1];
  const float* audio = (const float*)d_in[2];
  const float* fcos = (const float*)d_in[3];
  const float* fsin = (const float*)d_in[4];
  const float* norm1_w = (const float*)d_in[5];
  const float* norm2_w = (const float*)d_in[6];
  const float* norm3_w = (const float*)d_in[7];
  const float* W_qkv = (const float*)d_in[8];
  const float* W_sa = (const float*)d_in[9];
  const float* W_q = (const float*)d_in[10];
  const float* W_kv = (const float*)d_in[11];
  const float* W_ca = (const float*)d_in[12];
  const float* W_gate = (const float*)d_in[13];
  const float* W_up = (const float*)d_in[14];
  const float* W_down = (const float*)d_in[15];
  const float* adaW = (const float*)d_in[16];
  const float* adaB = (const float*)d_in[17];

  char* ws = (char*)d_ws;
  float* x_res = (float*)d_out;  // residual stream lives in d_out (fp32)

  unsigned short* wt_qkv = (unsigned short*)(ws + 0);
  unsigned short* wt_sa = (unsigned short*)(ws + 6291456);
  unsigned short* wt_q = (unsigned short*)(ws + 8388608);
  unsigned short* wt_kv = (unsigned short*)(ws + 10485760);
  unsigned short* wt_ca = (unsigned short*)(ws + 13631488);
  unsigned short* wt_gate = (unsigned short*)(ws + 15728640);  // + wt_up contiguous after
  unsigned short* wt_down = (unsigned short*)(ws + 32505856);
  unsigned short* audio_bf = (unsigned short*)(ws + 40894464);
  float* mods = (float*)(ws + 42467328);
  unsigned short* x_sa = (unsigned short*)(ws + 42516480);
  unsigned short* qkv = (unsigned short*)(ws + 50905088);
  unsigned short* vt_s = (unsigned short*)(ws + 76070912);
  unsigned short* sa = (unsigned short*)(ws + 84459520);
  unsigned short* xn = (unsigned short*)(ws + 42516480);
  unsigned short* qc = (unsigned short*)(ws + 50905088);
  unsigned short* kvc = (unsigned short*)(ws + 59293696);
  unsigned short* vt_c = (unsigned short*)(ws + 63488000);
  unsigned short* ca = (unsigned short*)(ws + 65585152);
  unsigned short* x_mlp = (unsigned short*)(ws + 42516480);
  unsigned short* gubuf = (unsigned short*)(ws + 50905088);  // 4096 x 8192 bf16 = 64MB

  // weight prep
  wtrans<<<dim3(96, 32), 256, 0, stream>>>(W_qkv, wt_qkv, 1024, 3072);
  wtrans<<<dim3(32, 32), 256, 0, stream>>>(W_sa, wt_sa, 1024, 1024);
  wtrans<<<dim3(32, 32), 256, 0, stream>>>(W_q, wt_q, 1024, 1024);
  wtrans<<<dim3(64, 24), 256, 0, stream>>>(W_kv, wt_kv, 768, 2048);
  wtrans<<<dim3(32, 32), 256, 0, stream>>>(W_ca, wt_ca, 1024, 1024);
  wtrans<<<dim3(128, 32), 256, 0, stream>>>(W_gate, wt_gate, 1024, 4096);
  wtrans<<<dim3(128, 32), 256, 0, stream>>>(W_up, wt_gate + 4194304, 1024, 4096);
  wtrans<<<dim3(32, 128), 256, 0, stream>>>(W_down, wt_down, 4096, 1024);
  f2bf_copy<<<768, 256, 0, stream>>>(audio, audio_bf, 786432);
  mods_kernel<<<dim3(24, 2), 256, 0, stream>>>(t_mod, adaW, adaB, mods);

  // self-attention block
  rmsnorm_mod<<<4096, 256, 0, stream>>>(x, norm1_w, mods, 0, 1024, x_sa);
  gemm_nt<0, 128><<<dim3(32, 24), 256, 0, stream>>>(x_sa, wt_qkv, qkv, nullptr, nullptr, 4096, 3072, 1024, 1024);
  rope_qk<<<dim3(2048, 2), 256, 0, stream>>>(qkv, fcos, fsin);
  vtrans<<<dim3(32, 16, 2), 256, 0, stream>>>(qkv + 2048, vt_s, 3072, 6291456, 2048);
  attn3<<<dim3(32, 16, 2), 256, 0, stream>>>(qkv, 3072, 6291456, qkv + 1024, 3072, 6291456,
                                             vt_s, sa, 1024, 2097152, 2048);
  gemm_nt<1, 64><<<dim3(32, 16), 256, 0, stream>>>(sa, wt_sa, x_res, x, mods + 2048, 4096, 1024, 1024, 1024);

  // cross-attention block
  rmsnorm_mod<<<4096, 256, 0, stream>>>(x_res, norm2_w, nullptr, 0, 0, xn);
  gemm_nt<0, 64><<<dim3(32, 16), 256, 0, stream>>>(xn, wt_q, qc, nullptr, nullptr, 4096, 1024, 1024, 1024);
  gemm_nt<0, 64><<<dim3(8, 32), 256, 0, stream>>>(audio_bf, wt_kv, kvc, nullptr, nullptr, 1024, 2048, 768, 768);
  vtrans<<<dim3(8, 16, 2), 256, 0, stream>>>(kvc + 1024, vt_c, 2048, 1048576, 512);
  attn3<<<dim3(32, 16, 2), 256, 0, stream>>>(qc, 1024, 2097152, kvc, 2048, 1048576, vt_c, ca,
                                             1024, 2097152, 512);
  gemm_nt<1, 64><<<dim3(32, 16), 256, 0, stream>>>(ca, wt_ca, x_res, x_res, nullptr, 4096, 1024, 1024, 1024);

  // MLP block (gate+up fused: weights contiguous, N=8192)
  rmsnorm_mod<<<4096, 256, 0, stream>>>(x_res, norm3_w, mods, 3072, 4096, x_mlp);
  gemm_nt<0, 128><<<dim3(32, 64), 256, 0, stream>>>(x_mlp, wt_gate, gubuf, nullptr, nullptr, 4096, 8192, 1024, 1024);
  swiglu2<<<dim3(2, 4096), 256, 0, stream>>>(gubuf);
  gemm_nt<1, 64><<<dim3(32, 16), 256, 0, stream>>>(gubuf, wt_down, x_res, x_res, mods + 5120, 4096, 1024, 4096, 8192);
}

// Round 5
// 669.975 us; speedup vs baseline: 1.9048x; 1.0215x over previous
//
#include <hip/hip_runtime.h>
#include <math.h>

// ---------- types ----------
typedef __attribute__((ext_vector_type(4))) float f32x4;
typedef __attribute__((ext_vector_type(4))) unsigned int u32x4;
typedef __attribute__((ext_vector_type(2))) unsigned int u32x2;
typedef __attribute__((ext_vector_type(8))) unsigned short u16x8;
typedef __attribute__((ext_vector_type(4))) unsigned short u16x4;
typedef __attribute__((ext_vector_type(8))) __bf16 bf16x8;

union F8 { u32x4 u; u16x8 us; bf16x8 v; };

__device__ __forceinline__ unsigned short f2bf(float f) {
  unsigned int u = __float_as_uint(f);
  u += 0x7fffu + ((u >> 16) & 1u);
  return (unsigned short)(u >> 16);
}
__device__ __forceinline__ float bf2f(unsigned short s) {
  return __uint_as_float(((unsigned int)s) << 16);
}

// async global->LDS, 16B per lane; lds dest = wave-uniform base + lane*16
__device__ __forceinline__ void ldsload16(const void* g, void* l) {
  __builtin_amdgcn_global_load_lds((const __attribute__((address_space(1))) unsigned int*)g,
                                   (__attribute__((address_space(3))) unsigned int*)l, 16, 0, 0);
}

// ---------- weight transpose+convert: in fp32 (K x N) -> out bf16 (row' x K) ----------
// remap=0: row'=n. remap=1: row' = ((n>>6)<<7) + (n&63) + radd  (gate/up interleave)
__global__ __launch_bounds__(256) void wtrans(const float* __restrict__ in,
                                              unsigned short* __restrict__ out,
                                              int K, int N, int remap, int radd) {
  __shared__ float tile[32][33];
  int tx = threadIdx.x & 31, ty = threadIdx.x >> 5;
  int n0 = blockIdx.x * 32, k0 = blockIdx.y * 32;
#pragma unroll
  for (int i = 0; i < 32; i += 8)
    tile[ty + i][tx] = in[(size_t)(k0 + ty + i) * N + n0 + tx];
  __syncthreads();
#pragma unroll
  for (int i = 0; i < 32; i += 8) {
    int n = n0 + ty + i;
    int rowp = remap ? (((n >> 6) << 7) + (n & 63) + radd) : n;
    out[(size_t)rowp * K + k0 + tx] = f2bf(tile[tx][ty + i]);
  }
}

// ---------- flat fp32 -> bf16 ----------
__global__ __launch_bounds__(256) void f2bf_copy(const float* __restrict__ in,
                                                 unsigned short* __restrict__ out, int n) {
  int i = (blockIdx.x * 256 + threadIdx.x) * 4;
  if (i < n) {
    f32x4 v = *(const f32x4*)(in + i);
    u16x4 o;
#pragma unroll
    for (int j = 0; j < 4; j++) o[j] = f2bf(v[j]);
    *(u16x4*)(out + i) = o;
  }
}

// ---------- mods = silu(t_mod) @ adaLN_W + adaLN_b ; (B x 6144) fp32 ----------
__global__ __launch_bounds__(256) void mods_kernel(const float* __restrict__ t_mod,
                                                   const float* __restrict__ W,
                                                   const float* __restrict__ bias,
                                                   float* __restrict__ mods) {
  int b = blockIdx.y;
  int j = blockIdx.x * 256 + threadIdx.x;
  __shared__ float a_s[1024];
  for (int i = threadIdx.x; i < 1024; i += 256) {
    float tv = t_mod[b * 1024 + i];
    a_s[i] = tv / (1.0f + expf(-tv));
  }
  __syncthreads();
  float acc = bias[j];
  for (int k = 0; k < 1024; k++) acc = fmaf(a_s[k], W[(size_t)k * 6144 + j], acc);
  mods[b * 6144 + j] = acc;
}

// ---------- rmsnorm (+ optional adaLN modulation), fp32 in -> bf16 out ----------
__global__ __launch_bounds__(256) void rmsnorm_mod(const float* __restrict__ x,
                                                   const float* __restrict__ w,
                                                   const float* mods, int shift_off,
                                                   int scale_off,
                                                   unsigned short* __restrict__ out) {
  int row = blockIdx.x;
  int b = row >> 11;
  const float* xr = x + (size_t)row * 1024;
  int t = threadIdx.x;
  f32x4 xv = *(const f32x4*)(xr + t * 4);
  float ss = xv[0] * xv[0] + xv[1] * xv[1] + xv[2] * xv[2] + xv[3] * xv[3];
#pragma unroll
  for (int off = 32; off >= 1; off >>= 1) ss += __shfl_xor(ss, off, 64);
  __shared__ float red[4];
  if ((t & 63) == 0) red[t >> 6] = ss;
  __syncthreads();
  float tot = red[0] + red[1] + red[2] + red[3];
  float rr = rsqrtf(tot * (1.0f / 1024.0f) + 1e-6f);
  f32x4 wv = *(const f32x4*)(w + t * 4);
  f32x4 scv = (f32x4)(0.0f), shv = (f32x4)(0.0f);
  if (mods) {
    scv = *(const f32x4*)(mods + b * 6144 + scale_off + t * 4);
    shv = *(const f32x4*)(mods + b * 6144 + shift_off + t * 4);
  }
  u16x4 ov;
#pragma unroll
  for (int j = 0; j < 4; j++) {
    float n = xv[j] * rr * wv[j];
    ov[j] = f2bf(n * (1.0f + scv[j]) + shv[j]);
  }
  *(u16x4*)(out + (size_t)row * 1024 + t * 4) = ov;
}

// ---------- GEMM: C = A(MxK,bf16,lda) * Bt(NxK,bf16)^T, LDS-transpose epilogue ----------
// EPI 0: bf16 store (ld N). EPI 1 (NT=64): fp32 out = res + gate*acc (ld N).
// EPI 2 (NT=128): fused swiglu; Bt rows interleaved [64 gate | 64 up]; bf16 out ld N/2.
template <int EPI, int NT>
__global__ __launch_bounds__(256) void gemm_nt(const unsigned short* __restrict__ A,
                                               const unsigned short* __restrict__ Bt,
                                               void* Cout, const float* res,
                                               const float* gate, int M, int N, int K,
                                               int lda) {
  constexpr int JT = NT / 32;
  constexpr int EC = NT + 4;
  __shared__ unsigned short As[128 * 32];
  __shared__ unsigned short Bs[NT * 32];
  __shared__ float eps[32][EC];
  int tid = threadIdx.x;
  int row0 = blockIdx.x * 128, col0 = blockIdx.y * NT;
  int wave = tid >> 6, lane = tid & 63;
  int wm = (wave & 1) * 64, wn = (wave >> 1) * (NT / 2);
  int mrow = lane & 15, grp = lane >> 4;
  f32x4 acc[4][JT];
#pragma unroll
  for (int i = 0; i < 4; i++)
#pragma unroll
    for (int j = 0; j < JT; j++) acc[i][j] = (f32x4)(0.0f);

  int sr = lane >> 2, skq = (lane & 3) * 8;
  const unsigned short* paG = A + (size_t)(row0 + wave * 32 + sr) * lda + skq;
  unsigned short* lA = &As[wave * 32 * 32];
  const unsigned short* pbG;
  unsigned short* lB;
  if (NT == 128) {
    pbG = Bt + (size_t)(col0 + wave * 32 + sr) * K + skq;
    lB = &Bs[wave * 32 * 32];
  } else {
    pbG = Bt + (size_t)(col0 + wave * 16 + sr) * K + skq;
    lB = &Bs[wave * 16 * 32];
  }

  for (int k0 = 0; k0 < K; k0 += 32) {
    __syncthreads();
    ldsload16(paG + k0, lA);
    ldsload16(paG + k0 + 16 * (size_t)lda, lA + 16 * 32);
    ldsload16(pbG + k0, lB);
    if (NT == 128) ldsload16(pbG + k0 + 16 * (size_t)K, lB + 16 * 32);
    __syncthreads();
    bf16x8 af[4], bfr[JT];
#pragma unroll
    for (int i = 0; i < 4; i++)
      af[i] = *(const bf16x8*)&As[(wm + i * 16 + mrow) * 32 + grp * 8];
#pragma unroll
    for (int j = 0; j < JT; j++)
      bfr[j] = *(const bf16x8*)&Bs[(wn + j * 16 + mrow) * 32 + grp * 8];
#pragma unroll
    for (int i = 0; i < 4; i++)
#pragma unroll
      for (int j = 0; j < JT; j++)
        acc[i][j] = __builtin_amdgcn_mfma_f32_16x16x32_bf16(af[i], bfr[j], acc[i][j], 0, 0, 0);
  }

  // epilogue: 4 passes of 32 rows through LDS, vectorized stores
  int rlw = (wave & 1) * 16 + grp * 4;
  int tr = tid >> 3, tc = (tid & 7) * 8;
#pragma unroll
  for (int p = 0; p < 4; p++) {
    __syncthreads();
#pragma unroll
    for (int j = 0; j < JT; j++)
#pragma unroll
      for (int r = 0; r < 4; r++) eps[rlw + r][wn + j * 16 + mrow] = acc[p][j][r];
    __syncthreads();
    int grow = row0 + (tr >> 4) * 64 + p * 16 + (tr & 15);
    if (EPI == 0) {
#pragma unroll
      for (int c = tc; c < NT; c += 64) {
        f32x4 v0 = *(const f32x4*)&eps[tr][c];
        f32x4 v1 = *(const f32x4*)&eps[tr][c + 4];
        u16x8 o;
#pragma unroll
        for (int j = 0; j < 4; j++) { o[j] = f2bf(v0[j]); o[j + 4] = f2bf(v1[j]); }
        *(u16x8*)&((unsigned short*)Cout)[(size_t)grow * N + col0 + c] = o;
      }
    } else if (EPI == 1) {
      int gc = col0 + tc;
      f32x4 v0 = *(const f32x4*)&eps[tr][tc];
      f32x4 v1 = *(const f32x4*)&eps[tr][tc + 4];
      const float* rp = res + (size_t)grow * N + gc;
      f32x4 r0 = *(const f32x4*)rp;
      f32x4 r1 = *(const f32x4*)(rp + 4);
      f32x4 g0 = (f32x4)(1.0f), g1 = (f32x4)(1.0f);
      if (gate) {
        const float* gp = gate + (grow >> 11) * 6144 + gc;
        g0 = *(const f32x4*)gp;
        g1 = *(const f32x4*)(gp + 4);
      }
      f32x4 o0, o1;
#pragma unroll
      for (int j = 0; j < 4; j++) {
        o0[j] = r0[j] + g0[j] * v0[j];
        o1[j] = r1[j] + g1[j] * v1[j];
      }
      float* op = (float*)Cout + (size_t)grow * N + gc;
      *(f32x4*)op = o0;
      *(f32x4*)(op + 4) = o1;
    } else {  // EPI == 2: silu(gate)*up, out ld = N/2
      f32x4 g0 = *(const f32x4*)&eps[tr][tc];
      f32x4 g1 = *(const f32x4*)&eps[tr][tc + 4];
      f32x4 u0 = *(const f32x4*)&eps[tr][64 + tc];
      f32x4 u1 = *(const f32x4*)&eps[tr][64 + tc + 4];
      u16x8 o;
#pragma unroll
      for (int j = 0; j < 4; j++) {
        float a = g0[j], b = g1[j];
        o[j] = f2bf(a / (1.0f + expf(-a)) * u0[j]);
        o[j + 4] = f2bf(b / (1.0f + expf(-b)) * u1[j]);
      }
      *(u16x8*)&((unsigned short*)Cout)[(size_t)grow * (N / 2) + (col0 >> 1) + tc] = o;
    }
  }
}

// ---------- V transpose: in bf16 [b][l][..h..][d] -> out bf16 [b*H+h][d][l] ----------
__global__ __launch_bounds__(256) void vtrans(const unsigned short* __restrict__ in,
                                              unsigned short* __restrict__ out,
                                              int lstride, size_t bstride, int Lk) {
  int lt = blockIdx.x, h = blockIdx.y, b = blockIdx.z;
  __shared__ unsigned short tile[64][72];
  int t = threadIdx.x;
  int lrow = t >> 2, dp = (t & 3) * 16;
  const unsigned short* src =
      in + (size_t)b * bstride + (size_t)(lt * 64 + lrow) * lstride + h * 64 + dp;
  u32x4 v0 = *(const u32x4*)src;
  u32x4 v1 = *(const u32x4*)(src + 8);
  *(u32x4*)&tile[lrow][dp] = v0;
  *(u32x4*)&tile[lrow][dp + 8] = v1;
  __syncthreads();
  int d = t >> 2, lp = (t & 3) * 16;
  u16x8 t0, t1;
#pragma unroll
  for (int i = 0; i < 8; i++) {
    t0[i] = tile[lp + i][d];
    t1[i] = tile[lp + 8 + i][d];
  }
  unsigned short* dst = out + ((size_t)(b * 16 + h) * 64 + d) * Lk + lt * 64 + lp;
  *(u16x8*)dst = t0;
  *(u16x8*)(dst + 8) = t1;
}

// ---------- RoPE applied in-place to q,k planes of qkv [b][l][3][16][64] ----------
__global__ __launch_bounds__(256) void rope_qk(unsigned short* __restrict__ qkv,
                                               const float* __restrict__ fcos,
                                               const float* __restrict__ fsin) {
  int l = blockIdx.x, b = blockIdx.y;
  int t = threadIdx.x;
  int plane = t >> 7, rem = t & 127;
  int hh = rem >> 3, off = (rem & 7) * 8;
  unsigned short* p = qkv + (((size_t)(b * 2048 + l) * 3 + plane) * 16 + hh) * 64 + off;
  F8 f;
  f.u = *(const u32x4*)p;
  f32x4 c = *(const f32x4*)(fcos + l * 32 + off / 2);
  f32x4 s = *(const f32x4*)(fsin + l * 32 + off / 2);
  u16x8 o;
#pragma unroll
  for (int j = 0; j < 4; j++) {
    float xr = bf2f(f.us[2 * j]), xi = bf2f(f.us[2 * j + 1]);
    o[2 * j] = f2bf(xr * c[j] - xi * s[j]);
    o[2 * j + 1] = f2bf(xr * s[j] + xi * c[j]);
  }
  *(u16x8*)p = o;
}

// ---------- flash attention v3: S^T softmax, ones-column l, 128-key tiles ----------
__global__ __launch_bounds__(256) void attn3(const unsigned short* __restrict__ qb, int q_ls,
                                             size_t q_bs, const unsigned short* __restrict__ kb,
                                             int k_ls, size_t k_bs,
                                             const unsigned short* __restrict__ vt,
                                             unsigned short* __restrict__ ob, int o_ls,
                                             size_t o_bs, int Lk) {
  int qt = blockIdx.x, h = blockIdx.y, b = blockIdx.z;
  int tid = threadIdx.x;
  int w = tid >> 6, lane = tid & 63;
  int mrow = lane & 15, grp = lane >> 4;
  int q0 = qt * 64 + w * 16;
  __shared__ unsigned short Ks[128][72];
  __shared__ unsigned short Vs[80][136];
  __shared__ unsigned short Ps[4][16][136];
  __shared__ float alf[4][16];

  const unsigned short* qp =
      qb + (size_t)b * q_bs + (size_t)(q0 + mrow) * q_ls + h * 64 + grp * 8;
  bf16x8 qf0, qf1;
  {
    F8 f;
    f.u = *(const u32x4*)qp;
    qf0 = f.v;
    f.u = *(const u32x4*)(qp + 32);
    qf1 = f.v;
  }
  const unsigned short* kbb = kb + (size_t)b * k_bs + h * 64;
  const unsigned short* vtb = vt + (size_t)(b * 16 + h) * 64 * Lk;

  {
    int r = 64 + (tid >> 4), c = (tid & 15) * 8;
    unsigned short val = (tid >> 4) == 0 ? (unsigned short)0x3F80 : (unsigned short)0;
    u16x8 vv;
#pragma unroll
    for (int j = 0; j < 8; j++) vv[j] = val;
    *(u16x8*)&Vs[r][c] = vv;
  }

  const float K2 = 0.125f * 1.4426950408889634f;
  float m_run = -INFINITY;
  f32x4 o[5];
#pragma unroll
  for (int nt = 0; nt < 5; nt++) o[nt] = (f32x4)(0.0f);

  int krow = tid >> 3, kcol = (tid & 7) * 8;
  int vrow = tid >> 4, vcol = (tid & 15) * 8;
  u32x4 kreg[4], vreg[4];
#pragma unroll
  for (int i = 0; i < 4; i++) {
    kreg[i] = *(const u32x4*)(kbb + (size_t)(krow + i * 32) * k_ls + kcol);
    vreg[i] = *(const u32x4*)(vtb + (size_t)(vrow + i * 16) * Lk + vcol);
  }

  for (int k0 = 0; k0 < Lk; k0 += 128) {
    __syncthreads();
#pragma unroll
    for (int i = 0; i < 4; i++) {
      *(u32x4*)&Ks[krow + i * 32][kcol] = kreg[i];
      *(u32x4*)&Vs[vrow + i * 16][vcol] = vreg[i];
    }
    __syncthreads();
    int kn = k0 + 128;
    if (kn < Lk) {
#pragma unroll
      for (int i = 0; i < 4; i++) {
        kreg[i] = *(const u32x4*)(kbb + (size_t)(kn + krow + i * 32) * k_ls + kcol);
        vreg[i] = *(const u32x4*)(vtb + (size_t)(vrow + i * 16) * Lk + kn + vcol);
      }
    }
    f32x4 sc[8];
#pragma unroll
    for (int si = 0; si < 8; si++) {
      F8 kf0, kf1;
      kf0.u = *(const u32x4*)&Ks[si * 16 + mrow][grp * 8];
      kf1.u = *(const u32x4*)&Ks[si * 16 + mrow][32 + grp * 8];
      f32x4 s = (f32x4)(0.0f);
      s = __builtin_amdgcn_mfma_f32_16x16x32_bf16(kf0.v, qf0, s, 0, 0, 0);
      s = __builtin_amdgcn_mfma_f32_16x16x32_bf16(kf1.v, qf1, s, 0, 0, 0);
      sc[si] = s;
    }
    f32x4 mv = sc[0];
#pragma unroll
    for (int si = 1; si < 8; si++) {
#pragma unroll
      for (int r = 0; r < 4; r++) mv[r] = fmaxf(mv[r], sc[si][r]);
    }
    float v = fmaxf(fmaxf(mv[0], mv[1]), fmaxf(mv[2], mv[3])) * K2;
    v = fmaxf(v, __shfl_xor(v, 16, 64));
    v = fmaxf(v, __shfl_xor(v, 32, 64));
    float mnew = fmaxf(m_run, v);
    float alpha = __builtin_amdgcn_exp2f(m_run - mnew);
    m_run = mnew;
    if (lane < 16) alf[w][lane] = alpha;
    float negm = -mnew;
#pragma unroll
    for (int si = 0; si < 8; si++) {
      float p0 = __builtin_amdgcn_exp2f(fmaf(sc[si][0], K2, negm));
      float p1 = __builtin_amdgcn_exp2f(fmaf(sc[si][1], K2, negm));
      float p2 = __builtin_amdgcn_exp2f(fmaf(sc[si][2], K2, negm));
      float p3 = __builtin_amdgcn_exp2f(fmaf(sc[si][3], K2, negm));
      u32x2 pk;
      pk[0] = (__float_as_uint(p0) >> 16) | (__float_as_uint(p1) & 0xFFFF0000u);
      pk[1] = (__float_as_uint(p2) >> 16) | (__float_as_uint(p3) & 0xFFFF0000u);
      *(u32x2*)&Ps[w][mrow][si * 16 + grp * 4] = pk;
    }
    f32x4 av = *(const f32x4*)&alf[w][grp * 4];
#pragma unroll
    for (int nt = 0; nt < 5; nt++) {
#pragma unroll
      for (int r = 0; r < 4; r++) o[nt][r] *= av[r];
    }
    bf16x8 pf[4];
#pragma unroll
    for (int kk = 0; kk < 4; kk++) {
      F8 f;
      f.u = *(const u32x4*)&Ps[w][mrow][kk * 32 + grp * 8];
      pf[kk] = f.v;
    }
#pragma unroll
    for (int nt = 0; nt < 5; nt++) {
#pragma unroll
      for (int kk = 0; kk < 4; kk++) {
        F8 vf;
        vf.u = *(const u32x4*)&Vs[nt * 16 + mrow][kk * 32 + grp * 8];
        o[nt] = __builtin_amdgcn_mfma_f32_16x16x32_bf16(pf[kk], vf.v, o[nt], 0, 0, 0);
      }
    }
  }
  float inv[4];
#pragma unroll
  for (int r = 0; r < 4; r++) {
    float lv = __shfl(o[4][r], lane & 48, 64);
    inv[r] = 1.0f / lv;
  }
  unsigned short* op = ob + (size_t)b * o_bs + h * 64;
#pragma unroll
  for (int nt = 0; nt < 4; nt++)
#pragma unroll
    for (int r = 0; r < 4; r++) {
      int row = q0 + grp * 4 + r;
      op[(size_t)row * o_ls + nt * 16 + mrow] = f2bf(o[nt][r] * inv[r]);
    }
}

// ---------- launcher ----------
extern "C" void kernel_launch(void* const* d_in, const int* in_sizes, int n_in, void* d_out,
                              int out_size, void* d_ws, size_t ws_size, hipStream_t stream) {
  const float* x = (const float*)d_in[0];
  const float* t_mod = (const float*)d_in[1];
  const float* audio = (const float*)d_in[2];
  const float* fcos = (const float*)d_in[3];
  const float* fsin = (const float*)d_in[4];
  const float* norm1_w = (const float*)d_in[5];
  const float* norm2_w = (const float*)d_in[6];
  const float* norm3_w = (const float*)d_in[7];
  const float* W_qkv = (const float*)d_in[8];
  const float* W_sa = (const float*)d_in[9];
  const float* W_q = (const float*)d_in[10];
  const float* W_kv = (const float*)d_in[11];
  const float* W_ca = (const float*)d_in[12];
  const float* W_gate = (const float*)d_in[13];
  const float* W_up = (const float*)d_in[14];
  const float* W_down = (const float*)d_in[15];
  const float* adaW = (const float*)d_in[16];
  const float* adaB = (const float*)d_in[17];

  char* ws = (char*)d_ws;
  float* x_res = (float*)d_out;  // residual stream lives in d_out (fp32)

  unsigned short* wt_qkv = (unsigned short*)(ws + 0);
  unsigned short* wt_sa = (unsigned short*)(ws + 6291456);
  unsigned short* wt_q = (unsigned short*)(ws + 8388608);
  unsigned short* wt_kv = (unsigned short*)(ws + 10485760);
  unsigned short* wt_ca = (unsigned short*)(ws + 13631488);
  unsigned short* wt_gu = (unsigned short*)(ws + 15728640);  // 8192x1024, gate/up interleaved
  unsigned short* wt_down = (unsigned short*)(ws + 32505856);
  unsigned short* audio_bf = (unsigned short*)(ws + 40894464);
  float* mods = (float*)(ws + 42467328);
  unsigned short* x_sa = (unsigned short*)(ws + 42516480);
  unsigned short* qkv = (unsigned short*)(ws + 50905088);
  unsigned short* vt_s = (unsigned short*)(ws + 76070912);
  unsigned short* sa = (unsigned short*)(ws + 84459520);
  unsigned short* xn = (unsigned short*)(ws + 42516480);
  unsigned short* qc = (unsigned short*)(ws + 50905088);
  unsigned short* kvc = (unsigned short*)(ws + 59293696);
  unsigned short* vt_c = (unsigned short*)(ws + 63488000);
  unsigned short* ca = (unsigned short*)(ws + 65585152);
  unsigned short* x_mlp = (unsigned short*)(ws + 42516480);
  unsigned short* hbuf = (unsigned short*)(ws + 50905088);  // 4096 x 4096 bf16 = 32MB

  // weight prep
  wtrans<<<dim3(96, 32), 256, 0, stream>>>(W_qkv, wt_qkv, 1024, 3072, 0, 0);
  wtrans<<<dim3(32, 32), 256, 0, stream>>>(W_sa, wt_sa, 1024, 1024, 0, 0);
  wtrans<<<dim3(32, 32), 256, 0, stream>>>(W_q, wt_q, 1024, 1024, 0, 0);
  wtrans<<<dim3(64, 24), 256, 0, stream>>>(W_kv, wt_kv, 768, 2048, 0, 0);
  wtrans<<<dim3(32, 32), 256, 0, stream>>>(W_ca, wt_ca, 1024, 1024, 0, 0);
  wtrans<<<dim3(128, 32), 256, 0, stream>>>(W_gate, wt_gu, 1024, 4096, 1, 0);
  wtrans<<<dim3(128, 32), 256, 0, stream>>>(W_up, wt_gu, 1024, 4096, 1, 64);
  wtrans<<<dim3(32, 128), 256, 0, stream>>>(W_down, wt_down, 4096, 1024, 0, 0);
  f2bf_copy<<<768, 256, 0, stream>>>(audio, audio_bf, 786432);
  mods_kernel<<<dim3(24, 2), 256, 0, stream>>>(t_mod, adaW, adaB, mods);

  // self-attention block
  rmsnorm_mod<<<4096, 256, 0, stream>>>(x, norm1_w, mods, 0, 1024, x_sa);
  gemm_nt<0, 128><<<dim3(32, 24), 256, 0, stream>>>(x_sa, wt_qkv, qkv, nullptr, nullptr, 4096, 3072, 1024, 1024);
  rope_qk<<<dim3(2048, 2), 256, 0, stream>>>(qkv, fcos, fsin);
  vtrans<<<dim3(32, 16, 2), 256, 0, stream>>>(qkv + 2048, vt_s, 3072, 6291456, 2048);
  attn3<<<dim3(32, 16, 2), 256, 0, stream>>>(qkv, 3072, 6291456, qkv + 1024, 3072, 6291456,
                                             vt_s, sa, 1024, 2097152, 2048);
  gemm_nt<1, 64><<<dim3(32, 16), 256, 0, stream>>>(sa, wt_sa, x_res, x, mods + 2048, 4096, 1024, 1024, 1024);

  // cross-attention block
  rmsnorm_mod<<<4096, 256, 0, stream>>>(x_res, norm2_w, nullptr, 0, 0, xn);
  gemm_nt<0, 64><<<dim3(32, 16), 256, 0, stream>>>(xn, wt_q, qc, nullptr, nullptr, 4096, 1024, 1024, 1024);
  gemm_nt<0, 64><<<dim3(8, 32), 256, 0, stream>>>(audio_bf, wt_kv, kvc, nullptr, nullptr, 1024, 2048, 768, 768);
  vtrans<<<dim3(8, 16, 2), 256, 0, stream>>>(kvc + 1024, vt_c, 2048, 1048576, 512);
  attn3<<<dim3(32, 16, 2), 256, 0, stream>>>(qc, 1024, 2097152, kvc, 2048, 1048576, vt_c, ca,
                                             1024, 2097152, 512);
  gemm_nt<1, 64><<<dim3(32, 16), 256, 0, stream>>>(ca, wt_ca, x_res, x_res, nullptr, 4096, 1024, 1024, 1024);

  // MLP block: gate+up fused with swiglu epilogue -> hbuf (4096x4096 bf16), then down
  rmsnorm_mod<<<4096, 256, 0, stream>>>(x_res, norm3_w, mods, 3072, 4096, x_mlp);
  gemm_nt<2, 128><<<dim3(32, 64), 256, 0, stream>>>(x_mlp, wt_gu, hbuf, nullptr, nullptr, 4096, 8192, 1024, 1024);
  gemm_nt<1, 64><<<dim3(32, 16), 256, 0, stream>>>(hbuf, wt_down, x_res, x_res, mods + 5120, 4096, 1024, 4096, 4096);
}

// Round 6
// 636.617 us; speedup vs baseline: 2.0046x; 1.0524x over previous
//
#include <hip/hip_runtime.h>
#include <math.h>

// ---------- types ----------
typedef __attribute__((ext_vector_type(4))) float f32x4;
typedef __attribute__((ext_vector_type(16))) float f32x16;
typedef __attribute__((ext_vector_type(4))) unsigned int u32x4;
typedef __attribute__((ext_vector_type(2))) unsigned int u32x2;
typedef __attribute__((ext_vector_type(8))) unsigned short u16x8;
typedef __attribute__((ext_vector_type(4))) unsigned short u16x4;
typedef __attribute__((ext_vector_type(8))) __bf16 bf16x8;

union F8 { u32x4 u; u16x8 us; bf16x8 v; };

#define LOG2E 1.4426950408889634f

__device__ __forceinline__ unsigned short f2bf(float f) {
  unsigned int u = __float_as_uint(f);
  u += 0x7fffu + ((u >> 16) & 1u);
  return (unsigned short)(u >> 16);
}
__device__ __forceinline__ float bf2f(unsigned short s) {
  return __uint_as_float(((unsigned int)s) << 16);
}

// async global->LDS, 16B per lane; lds dest = wave-uniform base + lane*16
__device__ __forceinline__ void ldsload16(const void* g, void* l) {
  __builtin_amdgcn_global_load_lds((const __attribute__((address_space(1))) unsigned int*)g,
                                   (__attribute__((address_space(3))) unsigned int*)l, 16, 0, 0);
}

// ---------- all weight transposes in one launch ----------
// in fp32 (K x N) -> out bf16 (row' x K); remap=1: row' = ((n>>6)<<7)+(n&63)+radd
struct WTDesc {
  const float* in;
  unsigned short* out;
  int K, N, remap, radd, tiles;
};
struct WTArgs { WTDesc d[8]; };

__global__ __launch_bounds__(256) void wtrans_all(WTArgs a) {
  __shared__ float tile[32][33];
  int t = blockIdx.x, i = 0;
  while (t >= a.d[i].tiles) { t -= a.d[i].tiles; i++; }
  const float* in = a.d[i].in;
  unsigned short* out = a.d[i].out;
  int K = a.d[i].K, N = a.d[i].N, remap = a.d[i].remap, radd = a.d[i].radd;
  int ntx = N >> 5;
  int n0 = (t % ntx) * 32, k0 = (t / ntx) * 32;
  int tx = threadIdx.x & 31, ty = threadIdx.x >> 5;
#pragma unroll
  for (int s = 0; s < 32; s += 8)
    tile[ty + s][tx] = in[(size_t)(k0 + ty + s) * N + n0 + tx];
  __syncthreads();
#pragma unroll
  for (int s = 0; s < 32; s += 8) {
    int n = n0 + ty + s;
    int rowp = remap ? (((n >> 6) << 7) + (n & 63) + radd) : n;
    out[(size_t)rowp * K + k0 + tx] = f2bf(tile[tx][ty + s]);
  }
}

// ---------- flat fp32 -> bf16 ----------
__global__ __launch_bounds__(256) void f2bf_copy(const float* __restrict__ in,
                                                 unsigned short* __restrict__ out, int n) {
  int i = (blockIdx.x * 256 + threadIdx.x) * 4;
  if (i < n) {
    f32x4 v = *(const f32x4*)(in + i);
    u16x4 o;
#pragma unroll
    for (int j = 0; j < 4; j++) o[j] = f2bf(v[j]);
    *(u16x4*)(out + i) = o;
  }
}

// ---------- mods = silu(t_mod) @ adaLN_W + adaLN_b ; (B x 6144) fp32 ----------
__global__ __launch_bounds__(256) void mods_kernel(const float* __restrict__ t_mod,
                                                   const float* __restrict__ W,
                                                   const float* __restrict__ bias,
                                                   float* __restrict__ mods) {
  int b = blockIdx.y;
  int j = blockIdx.x * 256 + threadIdx.x;
  __shared__ float a_s[1024];
  for (int i = threadIdx.x; i < 1024; i += 256) {
    float tv = t_mod[b * 1024 + i];
    a_s[i] = tv / (1.0f + expf(-tv));
  }
  __syncthreads();
  float acc = bias[j];
  for (int k = 0; k < 1024; k++) acc = fmaf(a_s[k], W[(size_t)k * 6144 + j], acc);
  mods[b * 6144 + j] = acc;
}

// ---------- rmsnorm (+ optional adaLN modulation), fp32 in -> bf16 out ----------
__global__ __launch_bounds__(256) void rmsnorm_mod(const float* __restrict__ x,
                                                   const float* __restrict__ w,
                                                   const float* mods, int shift_off,
                                                   int scale_off,
                                                   unsigned short* __restrict__ out) {
  int row = blockIdx.x;
  int b = row >> 11;
  const float* xr = x + (size_t)row * 1024;
  int t = threadIdx.x;
  f32x4 xv = *(const f32x4*)(xr + t * 4);
  float ss = xv[0] * xv[0] + xv[1] * xv[1] + xv[2] * xv[2] + xv[3] * xv[3];
#pragma unroll
  for (int off = 32; off >= 1; off >>= 1) ss += __shfl_xor(ss, off, 64);
  __shared__ float red[4];
  if ((t & 63) == 0) red[t >> 6] = ss;
  __syncthreads();
  float tot = red[0] + red[1] + red[2] + red[3];
  float rr = rsqrtf(tot * (1.0f / 1024.0f) + 1e-6f);
  f32x4 wv = *(const f32x4*)(w + t * 4);
  f32x4 scv = (f32x4)(0.0f), shv = (f32x4)(0.0f);
  if (mods) {
    scv = *(const f32x4*)(mods + b * 6144 + scale_off + t * 4);
    shv = *(const f32x4*)(mods + b * 6144 + shift_off + t * 4);
  }
  u16x4 ov;
#pragma unroll
  for (int j = 0; j < 4; j++) {
    float n = xv[j] * rr * wv[j];
    ov[j] = f2bf(n * (1.0f + scv[j]) + shv[j]);
  }
  *(u16x4*)(out + (size_t)row * 1024 + t * 4) = ov;
}

// ---------- GEMM (32x32x16 core): C = A(MxK,bf16,lda) * Bt(NxK,bf16)^T ----------
// EPI 0: bf16 store (ld N). EPI 1 (NT=64): fp32 out = res + gate*acc (ld N).
// EPI 2 (NT=128): fused swiglu, Bt rows interleaved [64 gate | 64 up], bf16 out ld N/2.
// EPI 3 (NT=128): bf16 store with RoPE on cols < 2048 (qkv).
template <int EPI, int NT>
__global__ __launch_bounds__(256) void gemm_nt(const unsigned short* __restrict__ A,
                                               const unsigned short* __restrict__ Bt,
                                               void* Cout, const float* res,
                                               const float* gate, const float* fcos,
                                               const float* fsin, int M, int N, int K,
                                               int lda) {
  constexpr int TJ = NT / 64;  // 32x32 col-tiles per wave
  __shared__ unsigned short As[128 * 32];
  __shared__ unsigned short Bs[NT * 32];
  __shared__ float eps[32][NT + 4];
  int tid = threadIdx.x;
  int row0 = blockIdx.x * 128, col0 = blockIdx.y * NT;
  int wave = tid >> 6, lane = tid & 63;
  int wm = (wave & 1) * 64, wn = (wave >> 1) * (NT / 2);
  int ln31 = lane & 31, lk8 = (lane >> 5) * 8;
  f32x16 acc[2][TJ];
#pragma unroll
  for (int i = 0; i < 2; i++)
#pragma unroll
    for (int j = 0; j < TJ; j++) acc[i][j] = (f32x16)(0.0f);

  int sr = lane >> 2, skq = (lane & 3) * 8;
  const unsigned short* paG = A + (size_t)(row0 + wave * 32 + sr) * lda + skq;
  unsigned short* lA = &As[wave * 32 * 32];
  const unsigned short* pbG;
  unsigned short* lB;
  if (NT == 128) {
    pbG = Bt + (size_t)(col0 + wave * 32 + sr) * K + skq;
    lB = &Bs[wave * 32 * 32];
  } else {
    pbG = Bt + (size_t)(col0 + wave * 16 + sr) * K + skq;
    lB = &Bs[wave * 16 * 32];
  }

  for (int k0 = 0; k0 < K; k0 += 32) {
    __syncthreads();
    ldsload16(paG + k0, lA);
    ldsload16(paG + k0 + 16 * (size_t)lda, lA + 16 * 32);
    ldsload16(pbG + k0, lB);
    if (NT == 128) ldsload16(pbG + k0 + 16 * (size_t)K, lB + 16 * 32);
    __syncthreads();
    bf16x8 af[2][2], bfr[TJ][2];
#pragma unroll
    for (int ti = 0; ti < 2; ti++)
#pragma unroll
      for (int ks = 0; ks < 2; ks++)
        af[ti][ks] = *(const bf16x8*)&As[(wm + ti * 32 + ln31) * 32 + lk8 + ks * 16];
#pragma unroll
    for (int tj = 0; tj < TJ; tj++)
#pragma unroll
      for (int ks = 0; ks < 2; ks++)
        bfr[tj][ks] = *(const bf16x8*)&Bs[(wn + tj * 32 + ln31) * 32 + lk8 + ks * 16];
#pragma unroll
    for (int ks = 0; ks < 2; ks++)
#pragma unroll
      for (int ti = 0; ti < 2; ti++)
#pragma unroll
        for (int tj = 0; tj < TJ; tj++)
          acc[ti][tj] = __builtin_amdgcn_mfma_f32_32x32x16_bf16(af[ti][ks], bfr[tj][ks],
                                                                acc[ti][tj], 0, 0, 0);
  }

  // epilogue: 4 passes of 32 rows through LDS, vectorized stores
  int tr = tid >> 3, tc = (tid & 7) * 8;
#pragma unroll
  for (int p = 0; p < 4; p++) {
    __syncthreads();
    if ((wave & 1) == (p >> 1)) {
      int ti = p & 1;
#pragma unroll
      for (int tj = 0; tj < TJ; tj++)
#pragma unroll
        for (int rg = 0; rg < 16; rg++) {
          int rl = (rg & 3) + 8 * (rg >> 2) + 4 * (lane >> 5);
          eps[rl][wn + tj * 32 + ln31] = acc[ti][tj][rg];
        }
    }
    __syncthreads();
    int grow = row0 + p * 32 + tr;
    if (EPI == 0 || EPI == 3) {
      bool rope = (EPI == 3) && (col0 < 2048);
      int l = grow & 2047;
#pragma unroll
      for (int c = tc; c < NT; c += 64) {
        f32x4 v0 = *(const f32x4*)&eps[tr][c];
        f32x4 v1 = *(const f32x4*)&eps[tr][c + 4];
        if (rope) {
          int d2 = ((col0 + c) & 63) >> 1;
          f32x4 cs = *(const f32x4*)(fcos + l * 32 + d2);
          f32x4 sn = *(const f32x4*)(fsin + l * 32 + d2);
          float a0 = v0[0], a1 = v0[1], a2 = v0[2], a3 = v0[3];
          v0[0] = a0 * cs[0] - a1 * sn[0];
          v0[1] = a0 * sn[0] + a1 * cs[0];
          v0[2] = a2 * cs[1] - a3 * sn[1];
          v0[3] = a2 * sn[1] + a3 * cs[1];
          float b0 = v1[0], b1 = v1[1], b2 = v1[2], b3 = v1[3];
          v1[0] = b0 * cs[2] - b1 * sn[2];
          v1[1] = b0 * sn[2] + b1 * cs[2];
          v1[2] = b2 * cs[3] - b3 * sn[3];
          v1[3] = b2 * sn[3] + b3 * cs[3];
        }
        u16x8 o;
#pragma unroll
        for (int j = 0; j < 4; j++) { o[j] = f2bf(v0[j]); o[j + 4] = f2bf(v1[j]); }
        *(u16x8*)&((unsigned short*)Cout)[(size_t)grow * N + col0 + c] = o;
      }
    } else if (EPI == 1) {
      int gc = col0 + tc;
      f32x4 v0 = *(const f32x4*)&eps[tr][tc];
      f32x4 v1 = *(const f32x4*)&eps[tr][tc + 4];
      const float* rp = res + (size_t)grow * N + gc;
      f32x4 r0 = *(const f32x4*)rp;
      f32x4 r1 = *(const f32x4*)(rp + 4);
      f32x4 g0 = (f32x4)(1.0f), g1 = (f32x4)(1.0f);
      if (gate) {
        const float* gp = gate + (grow >> 11) * 6144 + gc;
        g0 = *(const f32x4*)gp;
        g1 = *(const f32x4*)(gp + 4);
      }
      f32x4 o0, o1;
#pragma unroll
      for (int j = 0; j < 4; j++) {
        o0[j] = r0[j] + g0[j] * v0[j];
        o1[j] = r1[j] + g1[j] * v1[j];
      }
      float* op = (float*)Cout + (size_t)grow * N + gc;
      *(f32x4*)op = o0;
      *(f32x4*)(op + 4) = o1;
    } else {  // EPI == 2: silu(gate)*up, out ld = N/2
      f32x4 g0 = *(const f32x4*)&eps[tr][tc];
      f32x4 g1 = *(const f32x4*)&eps[tr][tc + 4];
      f32x4 u0 = *(const f32x4*)&eps[tr][64 + tc];
      f32x4 u1 = *(const f32x4*)&eps[tr][64 + tc + 4];
      u16x8 o;
#pragma unroll
      for (int j = 0; j < 4; j++) {
        float a = g0[j], b = g1[j];
        float ea = __builtin_amdgcn_exp2f(-a * LOG2E);
        float eb = __builtin_amdgcn_exp2f(-b * LOG2E);
        o[j] = f2bf(a * __builtin_amdgcn_rcpf(1.0f + ea) * u0[j]);
        o[j + 4] = f2bf(b * __builtin_amdgcn_rcpf(1.0f + eb) * u1[j]);
      }
      *(u16x8*)&((unsigned short*)Cout)[(size_t)grow * (N / 2) + (col0 >> 1) + tc] = o;
    }
  }
}

// ---------- V transpose: in bf16 [b][l][..h..][d] -> out bf16 [b*H+h][d][l] ----------
__global__ __launch_bounds__(256) void vtrans(const unsigned short* __restrict__ in,
                                              unsigned short* __restrict__ out,
                                              int lstride, size_t bstride, int Lk) {
  int lt = blockIdx.x, h = blockIdx.y, b = blockIdx.z;
  __shared__ unsigned short tile[64][72];
  int t = threadIdx.x;
  int lrow = t >> 2, dp = (t & 3) * 16;
  const unsigned short* src =
      in + (size_t)b * bstride + (size_t)(lt * 64 + lrow) * lstride + h * 64 + dp;
  u32x4 v0 = *(const u32x4*)src;
  u32x4 v1 = *(const u32x4*)(src + 8);
  *(u32x4*)&tile[lrow][dp] = v0;
  *(u32x4*)&tile[lrow][dp + 8] = v1;
  __syncthreads();
  int d = t >> 2, lp = (t & 3) * 16;
  u16x8 t0, t1;
#pragma unroll
  for (int i = 0; i < 8; i++) {
    t0[i] = tile[lp + i][d];
    t1[i] = tile[lp + 8 + i][d];
  }
  unsigned short* dst = out + ((size_t)(b * 16 + h) * 64 + d) * Lk + lt * 64 + lp;
  *(u16x8*)dst = t0;
  *(u16x8*)(dst + 8) = t1;
}

// ---------- flash attention v3: S^T softmax, ones-column l, 128-key tiles ----------
__global__ __launch_bounds__(256) void attn3(const unsigned short* __restrict__ qb, int q_ls,
                                             size_t q_bs, const unsigned short* __restrict__ kb,
                                             int k_ls, size_t k_bs,
                                             const unsigned short* __restrict__ vt,
                                             unsigned short* __restrict__ ob, int o_ls,
                                             size_t o_bs, int Lk) {
  int qt = blockIdx.x, h = blockIdx.y, b = blockIdx.z;
  int tid = threadIdx.x;
  int w = tid >> 6, lane = tid & 63;
  int mrow = lane & 15, grp = lane >> 4;
  int q0 = qt * 64 + w * 16;
  __shared__ unsigned short Ks[128][72];
  __shared__ unsigned short Vs[80][136];
  __shared__ unsigned short Ps[4][16][136];
  __shared__ float alf[4][16];

  const unsigned short* qp =
      qb + (size_t)b * q_bs + (size_t)(q0 + mrow) * q_ls + h * 64 + grp * 8;
  bf16x8 qf0, qf1;
  {
    F8 f;
    f.u = *(const u32x4*)qp;
    qf0 = f.v;
    f.u = *(const u32x4*)(qp + 32);
    qf1 = f.v;
  }
  const unsigned short* kbb = kb + (size_t)b * k_bs + h * 64;
  const unsigned short* vtb = vt + (size_t)(b * 16 + h) * 64 * Lk;

  {
    int r = 64 + (tid >> 4), c = (tid & 15) * 8;
    unsigned short val = (tid >> 4) == 0 ? (unsigned short)0x3F80 : (unsigned short)0;
    u16x8 vv;
#pragma unroll
    for (int j = 0; j < 8; j++) vv[j] = val;
    *(u16x8*)&Vs[r][c] = vv;
  }

  const float K2 = 0.125f * LOG2E;
  float m_run = -INFINITY;
  f32x4 o[5];
#pragma unroll
  for (int nt = 0; nt < 5; nt++) o[nt] = (f32x4)(0.0f);

  int krow = tid >> 3, kcol = (tid & 7) * 8;
  int vrow = tid >> 4, vcol = (tid & 15) * 8;
  u32x4 kreg[4], vreg[4];
#pragma unroll
  for (int i = 0; i < 4; i++) {
    kreg[i] = *(const u32x4*)(kbb + (size_t)(krow + i * 32) * k_ls + kcol);
    vreg[i] = *(const u32x4*)(vtb + (size_t)(vrow + i * 16) * Lk + vcol);
  }

  for (int k0 = 0; k0 < Lk; k0 += 128) {
    __syncthreads();
#pragma unroll
    for (int i = 0; i < 4; i++) {
      *(u32x4*)&Ks[krow + i * 32][kcol] = kreg[i];
      *(u32x4*)&Vs[vrow + i * 16][vcol] = vreg[i];
    }
    __syncthreads();
    int kn = k0 + 128;
    if (kn < Lk) {
#pragma unroll
      for (int i = 0; i < 4; i++) {
        kreg[i] = *(const u32x4*)(kbb + (size_t)(kn + krow + i * 32) * k_ls + kcol);
        vreg[i] = *(const u32x4*)(vtb + (size_t)(vrow + i * 16) * Lk + kn + vcol);
      }
    }
    f32x4 sc[8];
#pragma unroll
    for (int si = 0; si < 8; si++) {
      F8 kf0, kf1;
      kf0.u = *(const u32x4*)&Ks[si * 16 + mrow][grp * 8];
      kf1.u = *(const u32x4*)&Ks[si * 16 + mrow][32 + grp * 8];
      f32x4 s = (f32x4)(0.0f);
      s = __builtin_amdgcn_mfma_f32_16x16x32_bf16(kf0.v, qf0, s, 0, 0, 0);
      s = __builtin_amdgcn_mfma_f32_16x16x32_bf16(kf1.v, qf1, s, 0, 0, 0);
      sc[si] = s;
    }
    f32x4 mv = sc[0];
#pragma unroll
    for (int si = 1; si < 8; si++) {
#pragma unroll
      for (int r = 0; r < 4; r++) mv[r] = fmaxf(mv[r], sc[si][r]);
    }
    float v = fmaxf(fmaxf(mv[0], mv[1]), fmaxf(mv[2], mv[3])) * K2;
    v = fmaxf(v, __shfl_xor(v, 16, 64));
    v = fmaxf(v, __shfl_xor(v, 32, 64));
    float mnew = fmaxf(m_run, v);
    float alpha = __builtin_amdgcn_exp2f(m_run - mnew);
    m_run = mnew;
    if (lane < 16) alf[w][lane] = alpha;
    float negm = -mnew;
#pragma unroll
    for (int si = 0; si < 8; si++) {
      float p0 = __builtin_amdgcn_exp2f(fmaf(sc[si][0], K2, negm));
      float p1 = __builtin_amdgcn_exp2f(fmaf(sc[si][1], K2, negm));
      float p2 = __builtin_amdgcn_exp2f(fmaf(sc[si][2], K2, negm));
      float p3 = __builtin_amdgcn_exp2f(fmaf(sc[si][3], K2, negm));
      u32x2 pk;
      pk[0] = (__float_as_uint(p0) >> 16) | (__float_as_uint(p1) & 0xFFFF0000u);
      pk[1] = (__float_as_uint(p2) >> 16) | (__float_as_uint(p3) & 0xFFFF0000u);
      *(u32x2*)&Ps[w][mrow][si * 16 + grp * 4] = pk;
    }
    f32x4 av = *(const f32x4*)&alf[w][grp * 4];
#pragma unroll
    for (int nt = 0; nt < 5; nt++) {
#pragma unroll
      for (int r = 0; r < 4; r++) o[nt][r] *= av[r];
    }
    bf16x8 pf[4];
#pragma unroll
    for (int kk = 0; kk < 4; kk++) {
      F8 f;
      f.u = *(const u32x4*)&Ps[w][mrow][kk * 32 + grp * 8];
      pf[kk] = f.v;
    }
#pragma unroll
    for (int nt = 0; nt < 5; nt++) {
#pragma unroll
      for (int kk = 0; kk < 4; kk++) {
        F8 vf;
        vf.u = *(const u32x4*)&Vs[nt * 16 + mrow][kk * 32 + grp * 8];
        o[nt] = __builtin_amdgcn_mfma_f32_16x16x32_bf16(pf[kk], vf.v, o[nt], 0, 0, 0);
      }
    }
  }
  float inv[4];
#pragma unroll
  for (int r = 0; r < 4; r++) {
    float lv = __shfl(o[4][r], lane & 48, 64);
    inv[r] = 1.0f / lv;
  }
  unsigned short* op = ob + (size_t)b * o_bs + h * 64;
#pragma unroll
  for (int nt = 0; nt < 4; nt++)
#pragma unroll
    for (int r = 0; r < 4; r++) {
      int row = q0 + grp * 4 + r;
      op[(size_t)row * o_ls + nt * 16 + mrow] = f2bf(o[nt][r] * inv[r]);
    }
}

// ---------- launcher ----------
extern "C" void kernel_launch(void* const* d_in, const int* in_sizes, int n_in, void* d_out,
                              int out_size, void* d_ws, size_t ws_size, hipStream_t stream) {
  const float* x = (const float*)d_in[0];
  const float* t_mod = (const float*)d_in[1];
  const float* audio = (const float*)d_in[2];
  const float* fcos = (const float*)d_in[3];
  const float* fsin = (const float*)d_in[4];
  const float* norm1_w = (const float*)d_in[5];
  const float* norm2_w = (const float*)d_in[6];
  const float* norm3_w = (const float*)d_in[7];
  const float* W_qkv = (const float*)d_in[8];
  const float* W_sa = (const float*)d_in[9];
  const float* W_q = (const float*)d_in[10];
  const float* W_kv = (const float*)d_in[11];
  const float* W_ca = (const float*)d_in[12];
  const float* W_gate = (const float*)d_in[13];
  const float* W_up = (const float*)d_in[14];
  const float* W_down = (const float*)d_in[15];
  const float* adaW = (const float*)d_in[16];
  const float* adaB = (const float*)d_in[17];

  char* ws = (char*)d_ws;
  float* x_res = (float*)d_out;  // residual stream lives in d_out (fp32)

  unsigned short* wt_qkv = (unsigned short*)(ws + 0);
  unsigned short* wt_sa = (unsigned short*)(ws + 6291456);
  unsigned short* wt_q = (unsigned short*)(ws + 8388608);
  unsigned short* wt_kv = (unsigned short*)(ws + 10485760);
  unsigned short* wt_ca = (unsigned short*)(ws + 13631488);
  unsigned short* wt_gu = (unsigned short*)(ws + 15728640);  // 8192x1024, gate/up interleaved
  unsigned short* wt_down = (unsigned short*)(ws + 32505856);
  unsigned short* audio_bf = (unsigned short*)(ws + 40894464);
  float* mods = (float*)(ws + 42467328);
  unsigned short* x_sa = (unsigned short*)(ws + 42516480);
  unsigned short* qkv = (unsigned short*)(ws + 50905088);
  unsigned short* vt_s = (unsigned short*)(ws + 76070912);
  unsigned short* sa = (unsigned short*)(ws + 84459520);
  unsigned short* xn = (unsigned short*)(ws + 42516480);
  unsigned short* qc = (unsigned short*)(ws + 50905088);
  unsigned short* kvc = (unsigned short*)(ws + 59293696);
  unsigned short* vt_c = (unsigned short*)(ws + 63488000);
  unsigned short* ca = (unsigned short*)(ws + 65585152);
  unsigned short* x_mlp = (unsigned short*)(ws + 42516480);
  unsigned short* hbuf = (unsigned short*)(ws + 50905088);  // 4096 x 4096 bf16 = 32MB

  // weight prep: one launch for all transposes
  WTArgs wa;
  wa.d[0] = {W_qkv, wt_qkv, 1024, 3072, 0, 0, 96 * 32};
  wa.d[1] = {W_sa, wt_sa, 1024, 1024, 0, 0, 32 * 32};
  wa.d[2] = {W_q, wt_q, 1024, 1024, 0, 0, 32 * 32};
  wa.d[3] = {W_kv, wt_kv, 768, 2048, 0, 0, 64 * 24};
  wa.d[4] = {W_ca, wt_ca, 1024, 1024, 0, 0, 32 * 32};
  wa.d[5] = {W_gate, wt_gu, 1024, 4096, 1, 0, 128 * 32};
  wa.d[6] = {W_up, wt_gu, 1024, 4096, 1, 64, 128 * 32};
  wa.d[7] = {W_down, wt_down, 4096, 1024, 0, 0, 32 * 128};
  int total_tiles = 3072 + 1024 + 1024 + 1536 + 1024 + 4096 + 4096 + 4096;
  wtrans_all<<<total_tiles, 256, 0, stream>>>(wa);
  f2bf_copy<<<768, 256, 0, stream>>>(audio, audio_bf, 786432);
  mods_kernel<<<dim3(24, 2), 256, 0, stream>>>(t_mod, adaW, adaB, mods);

  // self-attention block
  rmsnorm_mod<<<4096, 256, 0, stream>>>(x, norm1_w, mods, 0, 1024, x_sa);
  gemm_nt<3, 128><<<dim3(32, 24), 256, 0, stream>>>(x_sa, wt_qkv, qkv, nullptr, nullptr,
                                                    fcos, fsin, 4096, 3072, 1024, 1024);
  vtrans<<<dim3(32, 16, 2), 256, 0, stream>>>(qkv + 2048, vt_s, 3072, 6291456, 2048);
  attn3<<<dim3(32, 16, 2), 256, 0, stream>>>(qkv, 3072, 6291456, qkv + 1024, 3072, 6291456,
                                             vt_s, sa, 1024, 2097152, 2048);
  gemm_nt<1, 64><<<dim3(32, 16), 256, 0, stream>>>(sa, wt_sa, x_res, x, mods + 2048, nullptr,
                                                   nullptr, 4096, 1024, 1024, 1024);

  // cross-attention block
  rmsnorm_mod<<<4096, 256, 0, stream>>>(x_res, norm2_w, nullptr, 0, 0, xn);
  gemm_nt<0, 64><<<dim3(32, 16), 256, 0, stream>>>(xn, wt_q, qc, nullptr, nullptr, nullptr,
                                                   nullptr, 4096, 1024, 1024, 1024);
  gemm_nt<0, 64><<<dim3(8, 32), 256, 0, stream>>>(audio_bf, wt_kv, kvc, nullptr, nullptr,
                                                  nullptr, nullptr, 1024, 2048, 768, 768);
  vtrans<<<dim3(8, 16, 2), 256, 0, stream>>>(kvc + 1024, vt_c, 2048, 1048576, 512);
  attn3<<<dim3(32, 16, 2), 256, 0, stream>>>(qc, 1024, 2097152, kvc, 2048, 1048576, vt_c, ca,
                                             1024, 2097152, 512);
  gemm_nt<1, 64><<<dim3(32, 16), 256, 0, stream>>>(ca, wt_ca, x_res, x_res, nullptr, nullptr,
                                                   nullptr, 4096, 1024, 1024, 1024);

  // MLP block: gate+up fused with swiglu epilogue -> hbuf (4096x4096 bf16), then down
  rmsnorm_mod<<<4096, 256, 0, stream>>>(x_res, norm3_w, mods, 3072, 4096, x_mlp);
  gemm_nt<2, 128><<<dim3(32, 64), 256, 0, stream>>>(x_mlp, wt_gu, hbuf, nullptr, nullptr,
                                                    nullptr, nullptr, 4096, 8192, 1024, 1024);
  gemm_nt<1, 64><<<dim3(32, 16), 256, 0, stream>>>(hbuf, wt_down, x_res, x_res, mods + 5120,
                                                   nullptr, nullptr, 4096, 1024, 4096, 4096);
}